// Round 9
// baseline (935.881 us; speedup 1.0000x reference)
//
#include <hip/hip_runtime.h>
#include <stdint.h>

// DualPrimalEdgePooling on MI355X — latency-restructured pipeline (30 dispatches).
// radix-select (fused in-block digit selection) -> worklist min-label CC ->
// fused flatten/scan/cluster -> shfl-broadcast segmented mean into compact psum ->
// edges+bitmap (block-agg count) -> popcount-prefix dual ranking (wave-batched) ->
// single finalize kernel streams the full 415 MB output.

#define N_NODES 200000
#define N_EDGES 600000
#define FDIM 128
#define NUM_POOL 300000u  // = E - NUM_KEEP

#define SC_NEEDEQ 3
#define SC_TIECNT 4
#define SC_C 5
#define SC_W 6
#define SC_U 7
#define SC_VCNT 8
#define SC_WL0 16        // per-round worklist counters: slots 16..24 (never reset)
#define TIECAP 4096
#define WLCAP 300800
#define HB 256           // hist grid blocks
#define NSB 98           // ceil(N/2048)

__device__ __forceinline__ uint32_t f2ou(float f){
  uint32_t b = __float_as_uint(f);
  return (b & 0x80000000u) ? ~b : (b | 0x80000000u);
}

// block-wide digit selection from a completed 256-bin histogram (blockDim=256)
static __device__ __forceinline__ void sel_level(const uint32_t* hist, uint32_t& target,
                                                 uint32_t& pfx, uint32_t* sm, uint32_t* res){
  int t = threadIdx.x;
  uint32_t cnt = hist[t];
  sm[t] = cnt; __syncthreads();
  for(int off = 1; off < 256; off <<= 1){
    uint32_t y = (t + off < 256) ? sm[t + off] : 0u;
    __syncthreads(); sm[t] += y; __syncthreads();
  }
  uint32_t suffix = sm[t];            // candidates with digit >= t
  uint32_t above  = suffix - cnt;
  if(above < target && target <= suffix){ res[0] = (uint32_t)t; res[1] = target - above; }
  __syncthreads();
  pfx = (pfx << 8) | res[0];
  target = res[1];
  __syncthreads();
}

// ---- tiny ws zero (sc + 4 hist arrays + counts) ----
__global__ __launch_bounds__(256) void k_zero(uint32_t* w, uint32_t nwords){
  uint32_t gid = blockIdx.x*256 + threadIdx.x;
  for(uint32_t j = gid; j < nwords; j += gridDim.x*256) w[j] = 0u;
}

// ---- selection: 4-level 8-bit radix histograms; prior-level digits recomputed in-block ----
template<int LEVEL>
__global__ __launch_bounds__(256) void k_hist8(const float* att, uint32_t* hists, int* L){
  __shared__ uint32_t h[256];
  __shared__ uint32_t sm[256];
  __shared__ uint32_t res[2];
  h[threadIdx.x] = 0;
  if(LEVEL == 1){
    for(int i = blockIdx.x*256 + threadIdx.x; i < N_NODES; i += HB*256) L[i] = i;  // fused CC init
  }
  __syncthreads();
  uint32_t pfx = 0, target = NUM_POOL;
  #pragma unroll
  for(int l = 0; l < LEVEL-1; ++l) sel_level(hists + 256*l, target, pfx, sm, res);
  constexpr int SH1 = (LEVEL > 1) ? 8*(5-LEVEL) : 0;
  constexpr int SH2 = 8*(4-LEVEL);
  for(int e = blockIdx.x*256 + threadIdx.x; e < N_EDGES; e += HB*256){
    uint32_t u = f2ou(att[e]);
    bool ok = (LEVEL == 1) || ((u >> SH1) == pfx);
    if(ok) atomicAdd(&h[(u >> SH2) & 0xFFu], 1u);
  }
  __syncthreads();
  uint32_t c = h[threadIdx.x];
  if(c) atomicAdd(&hists[256*(LEVEL-1) + threadIdx.x], c);
}

// ---- seed: recompute full threshold in-block; pooled edges hook + worklist; ties recorded ----
__global__ __launch_bounds__(256) void k_seed(const float* att, const int* src, const int* dst,
                       const uint32_t* hists, uint32_t* sc, uint32_t* tieIdx, int* L, uint2* wl){
  __shared__ uint32_t sm[256];
  __shared__ uint32_t res[2];
  uint32_t pfx = 0, target = NUM_POOL;
  #pragma unroll
  for(int l = 0; l < 4; ++l) sel_level(hists + 256*l, target, pfx, sm, res);
  if(blockIdx.x == 0 && threadIdx.x == 0) sc[SC_NEEDEQ] = target;
  uint32_t T = pfx;
  int e = blockIdx.x*256 + threadIdx.x;
  int lane = threadIdx.x & 63;
  bool app = false; int u = 0, v = 0;
  if(e < N_EDGES){
    uint32_t ub = f2ou(att[e]);
    if(ub > T){
      u = src[e]; v = dst[e];
      if(u != v){
        int m = u < v ? u : v, hi = u ^ v ^ m;
        atomicMin(&L[hi], m);
        app = true;
      }
    } else if(ub == T){
      uint32_t p = atomicAdd(&sc[SC_TIECNT], 1u);
      if(p < TIECAP) tieIdx[p] = (uint32_t)e;
    }
  }
  unsigned long long grp = __ballot(app);
  if(grp){
    int leader = __ffsll(grp) - 1;
    uint32_t base = 0;
    if(lane == leader) base = atomicAdd(&sc[SC_WL0], (uint32_t)__popcll(grp));
    base = (uint32_t)__shfl((int)base, leader);
    if(app){
      uint32_t off = (uint32_t)__popcll(grp & ((1ull << lane) - 1ull));
      wl[base + off] = make_uint2((uint32_t)(u < v ? u : v), (uint32_t)(u > v ? u : v));
    }
  }
}
__global__ __launch_bounds__(1024) void k_tiesel(uint32_t* sc, const uint32_t* tieIdx,
                        const int* src, const int* dst, int* L, uint2* wl){
  uint32_t m = sc[SC_TIECNT]; if(m > TIECAP) m = TIECAP;
  uint32_t need = sc[SC_NEEDEQ];
  int lane = threadIdx.x & 63;
  for(uint32_t i0 = 0; i0 < m; i0 += 1024){
    uint32_t i = i0 + threadIdx.x;
    bool app = false; int u = 0, v = 0;
    if(i < m){
      uint32_t mine = tieIdx[i];
      uint32_t r = 0;
      for(uint32_t j = 0; j < m; j++) r += (tieIdx[j] < mine) ? 1u : 0u;
      if(r < need){   // stable argsort: smallest indices pooled
        u = src[mine]; v = dst[mine];
        if(u != v){ int mm = u < v ? u : v, hi = u ^ v ^ mm; atomicMin(&L[hi], mm); app = true; }
      }
    }
    unsigned long long grp = __ballot(app);
    if(grp){
      int leader = __ffsll(grp) - 1;
      uint32_t base = 0;
      if(lane == leader) base = atomicAdd(&sc[SC_WL0], (uint32_t)__popcll(grp));
      base = (uint32_t)__shfl((int)base, leader);
      if(app){
        uint32_t off = (uint32_t)__popcll(grp & ((1ull << lane) - 1ull));
        wl[base + off] = make_uint2((uint32_t)(u < v ? u : v), (uint32_t)(u > v ? u : v));
      }
    }
  }
}
// loop-free relax: 4-level chase (plain loads), one-shot hooking atomicMin, survivors re-appended.
__global__ __launch_bounds__(256) void k_relax(const uint2* wl_in, uint2* wl_out, int* L,
                       uint32_t* sc, int inSlot, int outSlot){
  uint32_t n = sc[inSlot];
  int lane = threadIdx.x & 63;
  for(uint32_t base = blockIdx.x*256u; base < n; base += gridDim.x*256u){
    uint32_t idx = base + threadIdx.x;
    bool active = idx < n;
    int lu = 0, lv = 0;
    if(active){
      uint2 ed = wl_in[idx];
      lu = L[ed.x]; lu = L[lu]; lu = L[lu]; lu = L[lu];
      lv = L[ed.y]; lv = L[lv]; lv = L[lv]; lv = L[lv];
      active = (lu != lv);
      if(active){
        int m = lu < lv ? lu : lv, hi = lu ^ lv ^ m;
        atomicMin(&L[hi], m);
      }
    }
    unsigned long long grp = __ballot(active);
    if(grp){
      int leader = __ffsll(grp) - 1;
      uint32_t b = 0;
      if(lane == leader) b = atomicAdd(&sc[outSlot], (uint32_t)__popcll(grp));
      b = (uint32_t)__shfl((int)b, leader);
      if(active){
        uint32_t off = (uint32_t)__popcll(grp & ((1ull << lane) - 1ull));
        wl_out[b + off] = make_uint2((uint32_t)(lu < lv ? lu : lv), (uint32_t)(lu > lv ? lu : lv));
      }
    }
  }
}
// pointer jumping (6-level), skipped entirely if worklist already empty
__global__ void k_jump(int* L, const uint32_t* sc, int liveSlot){
  if(sc[liveSlot] == 0) return;
  int i = blockIdx.x*256 + threadIdx.x;
  if(i >= N_NODES) return;
  int v = L[i]; v = L[v]; v = L[v]; v = L[v]; v = L[v]; v = L[v];
  L[i] = v;
}
// flatten to roots + per-block root-count reduction (2048 nodes/block)
__global__ __launch_bounds__(256) void k_flatten_reduce(int* L, uint32_t* bsums){
  uint32_t base = blockIdx.x*2048u + threadIdx.x*8u;
  uint32_t s = 0;
  #pragma unroll
  for(int k = 0; k < 8; k++){
    uint32_t i = base + k;
    if(i < N_NODES){
      int p = L[i]; int q = L[p];
      while(q != p){ p = q; q = L[p]; }
      L[i] = p;
      s += (p == (int)i) ? 1u : 0u;
    }
  }
  __shared__ uint32_t sm[256];
  sm[threadIdx.x] = s; __syncthreads();
  for(int off = 128; off > 0; off >>= 1){
    if((int)threadIdx.x < off) sm[threadIdx.x] += sm[threadIdx.x + off];
    __syncthreads();
  }
  if(threadIdx.x == 0) bsums[blockIdx.x] = sm[0];
}

// ---- 2-kernel scans. MODE 0: counts->cursor. MODE 1: popc(bitmap)->wpref (+SC_U).
//      MODE 2: rootflag(L)->rank_ (+SC_C,SC_W). apply scans bsums in-LDS itself. ----
template<int MODE>
__global__ __launch_bounds__(256) void k_scan_reduce(const uint32_t* in, uint32_t* bsums,
                       const uint32_t* sc, float* dsum, uint32_t* dcnt){
  uint32_t n = (MODE == 1) ? sc[SC_W] : N_NODES;
  if(MODE == 1){  // lazy-zero compact dual accumulators (VCNT rows >= U)
    uint32_t vc = sc[SC_VCNT];
    size_t gid = (size_t)blockIdx.x*256 + threadIdx.x, gs = (size_t)gridDim.x*256;
    for(size_t j = gid; j < (size_t)vc*FDIM; j += gs) dsum[j] = 0.f;
    for(size_t j = gid; j < vc; j += gs) dcnt[j] = 0u;
  }
  uint32_t base = blockIdx.x*2048u + threadIdx.x*8u;
  uint32_t s = 0;
  #pragma unroll
  for(int k = 0; k < 8; k++){
    uint32_t idx = base + k;
    if(idx < n){ uint32_t v = in[idx]; if(MODE == 1) v = __popc(v); s += v; }
  }
  __shared__ uint32_t sm[256];
  sm[threadIdx.x] = s; __syncthreads();
  for(int off = 128; off > 0; off >>= 1){
    if((int)threadIdx.x < off) sm[threadIdx.x] += sm[threadIdx.x + off];
    __syncthreads();
  }
  if(threadIdx.x == 0) bsums[blockIdx.x] = sm[0];
}
template<int MODE>
__global__ __launch_bounds__(256) void k_scan_apply(const uint32_t* in, const int* L,
                       const uint32_t* bsums, int nb, uint32_t* out, uint32_t* sc){
  __shared__ uint32_t bs[4096];
  __shared__ uint32_t sm[256];
  int t = threadIdx.x;
  uint32_t n = (MODE == 1) ? sc[SC_W] : N_NODES;
  uint32_t loc[16]; uint32_t ls = 0;
  #pragma unroll
  for(int k = 0; k < 16; k++){ int idx = t*16 + k; uint32_t v = (idx < nb) ? bsums[idx] : 0u; loc[k] = v; ls += v; }
  sm[t] = ls; __syncthreads();
  for(int off = 1; off < 256; off <<= 1){
    uint32_t y = (t >= off) ? sm[t - off] : 0u;
    __syncthreads(); sm[t] += y; __syncthreads();
  }
  uint32_t total = sm[255];
  uint32_t run = sm[t] - ls;
  #pragma unroll
  for(int k = 0; k < 16; k++){ bs[t*16 + k] = run; run += loc[k]; }
  __syncthreads();
  uint32_t blockbase = bs[blockIdx.x];
  __syncthreads();
  uint32_t base = blockIdx.x*2048u + t*8u;
  uint32_t xs[8]; uint32_t ts2 = 0;
  #pragma unroll
  for(int k = 0; k < 8; k++){
    uint32_t idx = base + k; uint32_t v = 0;
    if(idx < n){
      if(MODE == 2) v = (L[idx] == (int)idx) ? 1u : 0u;
      else { v = in[idx]; if(MODE == 1) v = __popc(v); }
    }
    xs[k] = v; ts2 += v;
  }
  sm[t] = ts2; __syncthreads();
  for(int off = 1; off < 256; off <<= 1){
    uint32_t y = (t >= off) ? sm[t - off] : 0u;
    __syncthreads(); sm[t] += y; __syncthreads();
  }
  uint32_t run2 = blockbase + sm[t] - ts2;
  #pragma unroll
  for(int k = 0; k < 8; k++){ uint32_t idx = base + k; if(idx < n) out[idx] = run2; run2 += xs[k]; }
  if(blockIdx.x == 0 && t == 0){
    if(MODE == 2){ sc[SC_C] = total; uint64_t cc = (uint64_t)total*(uint64_t)total; sc[SC_W] = (uint32_t)((cc + 31ull) >> 5); }
    if(MODE == 1){ sc[SC_U] = total; }
  }
}

// ---- cluster ids + wave-agg counts + lazy zero of psum[0..C*F) and bitmap[0..W) ----
__global__ __launch_bounds__(256) void k_cluster_counts(const int* L, const uint32_t* rank_,
                       int* cluster_i, float* outC, uint32_t* counts, float* psum,
                       uint32_t* bitmap, const uint32_t* sc){
  uint32_t C = sc[SC_C], W = sc[SC_W];
  uint32_t gid = blockIdx.x*256 + threadIdx.x, gs = gridDim.x*256;
  for(size_t j = gid; j < (size_t)C*FDIM; j += gs) psum[j] = 0.f;
  for(uint32_t j = gid; j < W; j += gs) bitmap[j] = 0u;
  int i = (int)gid;
  int lane = threadIdx.x & 63;
  int c = -1;
  if(i < N_NODES){
    c = (int)rank_[L[i]];
    cluster_i[i] = c;
    outC[i] = (float)c;
  }
  unsigned long long remaining = __ballot(i < N_NODES);
  while(remaining){
    int leader = __ffsll(remaining) - 1;
    int lc = __shfl(c, leader);
    unsigned long long grp = __ballot(c == lc) & remaining;
    if(lane == leader) atomicAdd(&counts[lc], (uint32_t)__popcll(grp));
    remaining &= ~grp;
  }
}
__global__ void k_scatter(const int* cluster_i, uint32_t* cursor, uint32_t* order){
  int i = blockIdx.x*256 + threadIdx.x;
  int lane = threadIdx.x & 63;
  int c = (i < N_NODES) ? cluster_i[i] : -1;
  unsigned long long remaining = __ballot(i < N_NODES);
  while(remaining){
    int leader = __ffsll(remaining) - 1;
    int lc = __shfl(c, leader);
    unsigned long long grp = __ballot(c == lc) & remaining;
    int b = 0;
    if(lane == leader) b = (int)atomicAdd(&cursor[lc], (uint32_t)__popcll(grp));
    b = __shfl(b, leader);
    if((grp >> lane) & 1ull){
      uint32_t sub = (uint32_t)__popcll(grp & ((1ull << lane) - 1ull));
      order[(uint32_t)b + sub] = (uint32_t)i;
    }
    remaining &= ~grp;
  }
}

// ---- segmented mean: 32 rows/wave; order+cluster preloaded per-lane, shfl-broadcast ----
__global__ __launch_bounds__(256) void k_segsum(const float* px, const uint32_t* order,
        const int* cluster_i, float* psum){
  int wave = (int)((blockIdx.x*256u + threadIdx.x) >> 6);
  int lane = threadIdx.x & 63;
  int start = wave * 32;
  if(start >= N_NODES) return;
  int cnt = N_NODES - start; if(cnt > 32) cnt = 32;
  uint32_t ordv = 0; int cv = -1;
  if(lane < cnt){ ordv = order[start + lane]; cv = cluster_i[ordv]; }
  float ax = 0.f, ay = 0.f; int cur = -1;
  for(int r = 0; r < cnt; r++){
    uint32_t i = (uint32_t)__shfl((int)ordv, r);
    int c = __shfl(cv, r);
    if(c != cur){
      if(cur >= 0){
        atomicAdd(&psum[(size_t)cur*FDIM + 2*lane], ax);
        atomicAdd(&psum[(size_t)cur*FDIM + 2*lane + 1], ay);
      }
      cur = c; ax = 0.f; ay = 0.f;
    }
    float2 v = ((const float2*)(px + (size_t)i*FDIM))[lane];
    ax += v.x; ay += v.y;
  }
  if(cur >= 0){
    atomicAdd(&psum[(size_t)cur*FDIM + 2*lane], ax);
    atomicAdd(&psum[(size_t)cur*FDIM + 2*lane + 1], ay);
  }
}

// ---- edges: rebuilt edge index + pair-key bitmap; one count atomic per block ----
__global__ __launch_bounds__(256) void k_edges(const int* src, const int* dst,
        const int* cluster_i, uint32_t* sc, float* outE, uint32_t* kc, uint32_t* bitmap){
  __shared__ uint32_t wsum[4];
  int e = blockIdx.x*256 + threadIdx.x;
  int lane = threadIdx.x & 63;
  int wv = threadIdx.x >> 6;
  bool val = false;
  if(e < N_EDGES){
    int cu = cluster_i[src[e]];
    int cv = cluster_i[dst[e]];
    val = (cu != cv);
    outE[e] = val ? (float)cu : -1.0f;
    outE[N_EDGES + e] = val ? (float)cv : -1.0f;
    if(val){
      int a = cu < cv ? cu : cv, b = cu < cv ? cv : cu;
      uint32_t C = sc[SC_C];
      uint32_t key = (uint32_t)a * C + (uint32_t)b;
      kc[e] = key;
      atomicOr(&bitmap[key >> 5], 1u << (key & 31u));
    } else {
      kc[e] = 0xFFFFFFFFu;
    }
  }
  unsigned long long grp = __ballot(val);
  if(lane == 0) wsum[wv] = (uint32_t)__popcll(grp);
  __syncthreads();
  if(threadIdx.x == 0){
    uint32_t s = wsum[0] + wsum[1] + wsum[2] + wsum[3];
    if(s) atomicAdd(&sc[SC_VCNT], s);   // fire-and-forget (upper bound for dsum zeroing)
  }
}

// ---- dual accumulate: 64 edges/wave, ballot + shfl-broadcast rank ----
__global__ __launch_bounds__(256) void k_dualacc(const float* dx, const uint32_t* kc,
                          const uint32_t* bitmap, const uint32_t* wpref,
                          float* dsum, uint32_t* dcnt){
  int wave = (int)((blockIdx.x*256u + threadIdx.x) >> 6);
  int lane = threadIdx.x & 63;
  int base = wave * 64;
  if(base >= N_EDGES) return;
  int e = base + lane;
  uint32_t key = (e < N_EDGES) ? kc[e] : 0xFFFFFFFFu;
  bool val = (key != 0xFFFFFFFFu);
  uint32_t r = 0;
  if(val){
    uint32_t wi = key >> 5, bi = key & 31u;
    r = wpref[wi] + __popc(bitmap[wi] & ((1u << bi) - 1u));
  }
  unsigned long long m = __ballot(val);
  while(m){
    int b = __ffsll(m) - 1;
    m &= m - 1;
    uint32_t ee = (uint32_t)(base + b);
    uint32_t rr = (uint32_t)__shfl((int)r, b);
    float2 v = ((const float2*)(dx + (size_t)ee*FDIM))[lane];
    atomicAdd(&dsum[(size_t)rr*FDIM + 2*lane], v.x);
    atomicAdd(&dsum[(size_t)rr*FDIM + 2*lane + 1], v.y);
    if(lane == 0) atomicAdd(&dcnt[rr], 1u);
  }
}
// ---- stream the full output region: means for live rows, zeros elsewhere ----
__global__ __launch_bounds__(256) void k_finalize(const float4* psum, const uint32_t* counts,
        const float4* dsum, const uint32_t* dcnt, const uint32_t* sc, float4* out4){
  uint32_t C = sc[SC_C], U = sc[SC_U];
  size_t gid = (size_t)blockIdx.x*256 + threadIdx.x;
  size_t gs = (size_t)gridDim.x*256;
  const size_t NP4 = (size_t)N_NODES*(FDIM/4);
  const size_t TOT4 = (size_t)(N_NODES + N_EDGES)*(FDIM/4);
  for(size_t j = gid; j < TOT4; j += gs){
    float4 v = make_float4(0.f,0.f,0.f,0.f);
    if(j < NP4){
      uint32_t r = (uint32_t)(j >> 5);
      if(r < C){
        v = psum[j];
        float fc = (float)counts[r];
        v.x /= fc; v.y /= fc; v.z /= fc; v.w /= fc;
      }
    } else {
      size_t dj = j - NP4;
      uint32_t r = (uint32_t)(dj >> 5);
      if(r < U){
        v = dsum[dj];
        float fc = (float)dcnt[r];
        v.x /= fc; v.y /= fc; v.z /= fc; v.w /= fc;
      }
    }
    out4[j] = v;
  }
}

extern "C" void kernel_launch(void* const* d_in, const int* in_sizes, int n_in,
                              void* d_out, int out_size, void* d_ws, size_t ws_size,
                              hipStream_t stream){
  (void)in_sizes; (void)n_in; (void)out_size;
  const float* primal_x = (const float*)d_in[0];
  const float* dual_x   = (const float*)d_in[1];
  const float* att      = (const float*)d_in[2];
  const int*   pei      = (const int*)d_in[3];
  const int* src = pei;
  const int* dst = pei + N_EDGES;

  float* out  = (float*)d_out;
  float* outE = out + (size_t)(N_NODES + N_EDGES)*FDIM;   // (2, E)
  float* outC = outE + (size_t)2*N_EDGES;                 // (N,)

  uint32_t* w = (uint32_t*)d_ws;
  size_t words_avail = ws_size / 4;
  const size_t FIXED = 64 + 1024 + (size_t)N_NODES
                     + TIECAP + 5*(size_t)N_NODES + 4*(size_t)WLCAP
                     + (size_t)N_EDGES + (size_t)N_EDGES   // kc + dcnt
                     + 4096
                     + (size_t)N_NODES*FDIM + (size_t)N_EDGES*FDIM;  // psum+dsum
  size_t wcap = (words_avail > FIXED) ? (words_avail - FIXED)/2 : 4;
  if(wcap > 8388608) wcap = 8388608;   // supports C up to 16384
  wcap &= ~(size_t)3;

  size_t o = 0;
  uint32_t* sc     = w;               o += 64;
  uint32_t* hists  = w + o;           o += 1024;          // 4 x 256
  uint32_t* counts = w + o;           o += N_NODES;
  size_t zero_words = o;                                   // zeroed per call
  uint32_t* tieIdx = w + o;           o += TIECAP;
  int* labels      = (int*)(w + o);   o += N_NODES;
  uint32_t* rank_  = w + o;           o += N_NODES;
  uint32_t* cursor = w + o;           o += N_NODES;
  int* cluster_i   = (int*)(w + o);   o += N_NODES;
  uint32_t* order  = w + o;           o += N_NODES;
  uint2* wl0       = (uint2*)(w + o); o += 2*(size_t)WLCAP;
  uint2* wl1       = (uint2*)(w + o); o += 2*(size_t)WLCAP;
  uint32_t* kc     = w + o;           o += N_EDGES;
  uint32_t* dcnt   = w + o;           o += N_EDGES;
  uint32_t* bsums  = w + o;           o += 4096;
  float* psum      = (float*)(w + o); o += (size_t)N_NODES*FDIM;
  float* dsum      = (float*)(w + o); o += (size_t)N_EDGES*FDIM;
  uint32_t* bitmap = w + o;           o += wcap;
  uint32_t* wpref  = w + o;           o += wcap;

  const int EB  = (N_EDGES + 255)/256;
  const int NB  = (N_NODES + 255)/256;
  const int SGB = (N_NODES + 32*4 - 1)/(32*4);   // 32 rows/wave, 4 waves/block = 1563
  const int WSB = (int)((wcap + 2047)/2048);     // <= 4096

  k_zero<<<64,256,0,stream>>>(w, (uint32_t)zero_words);
  // selection: 4 hist levels (prior digits recomputed in-block; L init fused in L1)
  k_hist8<1><<<HB,256,0,stream>>>(att, hists, labels);
  k_hist8<2><<<HB,256,0,stream>>>(att, hists, labels);
  k_hist8<3><<<HB,256,0,stream>>>(att, hists, labels);
  k_hist8<4><<<HB,256,0,stream>>>(att, hists, labels);
  // CC: seed + tie handling + relax/jump ladder (per-round counter slots, never reset)
  k_seed<<<EB,256,0,stream>>>(att, src, dst, hists, sc, tieIdx, labels, wl0);
  k_tiesel<<<1,1024,0,stream>>>(sc, tieIdx, src, dst, labels, wl0);
  for(int r = 1; r <= 8; ++r){
    uint2* win  = (r & 1) ? wl0 : wl1;
    uint2* wout = (r & 1) ? wl1 : wl0;
    k_relax<<<1024,256,0,stream>>>(win, wout, labels, sc, SC_WL0 + r - 1, SC_WL0 + r);
    if(r <= 3) k_jump<<<NB,256,0,stream>>>(labels, sc, SC_WL0 + r);
  }
  k_flatten_reduce<<<NSB,256,0,stream>>>(labels, bsums);
  k_scan_apply<2><<<NSB,256,0,stream>>>(counts, labels, bsums, NSB, rank_, sc);   // -> rank_, SC_C, SC_W
  k_cluster_counts<<<NB,256,0,stream>>>(labels, rank_, cluster_i, outC, counts, psum, bitmap, sc);
  k_scan_reduce<0><<<NSB,256,0,stream>>>(counts, bsums, sc, dsum, dcnt);
  k_scan_apply<0><<<NSB,256,0,stream>>>(counts, labels, bsums, NSB, cursor, sc);  // -> cursor
  k_scatter<<<NB,256,0,stream>>>(cluster_i, cursor, order);
  k_segsum<<<SGB,256,0,stream>>>(primal_x, order, cluster_i, psum);
  k_edges<<<EB,256,0,stream>>>(src, dst, cluster_i, sc, outE, kc, bitmap);
  k_scan_reduce<1><<<WSB,256,0,stream>>>(bitmap, bsums, sc, dsum, dcnt);          // + lazy zero dsum/dcnt
  k_scan_apply<1><<<WSB,256,0,stream>>>(bitmap, labels, bsums, WSB, wpref, sc);   // -> wpref, SC_U
  k_dualacc<<<EB,256,0,stream>>>(dual_x, kc, bitmap, wpref, dsum, dcnt);
  k_finalize<<<2048,256,0,stream>>>((const float4*)psum, counts, (const float4*)dsum,
                                    dcnt, sc, (float4*)out);
}

// Round 10
// 724.546 us; speedup vs baseline: 1.2917x; 1.2917x over previous
//
#include <hip/hip_runtime.h>
#include <stdint.h>

// DualPrimalEdgePooling on MI355X — atomic-depth-limited pipeline (30 dispatches).
// radix-select -> worklist min-label CC -> fused flatten/scan/cluster ->
// 128-rows/wave shfl-broadcast segmented mean into 8 shadow accumulators ->
// edges+bitmap -> popcount-prefix dual ranking -> finalize streams output.

#define N_NODES 200000
#define N_EDGES 600000
#define FDIM 128
#define NUM_POOL 300000u  // = E - NUM_KEEP

#define SC_NEEDEQ 3
#define SC_TIECNT 4
#define SC_C 5
#define SC_W 6
#define SC_U 7
#define SC_VCNT 8
#define SC_WL0 16        // per-round worklist counters: slots 16..24 (never reset)
#define TIECAP 4096
#define WLCAP 300800
#define HB 256           // hist grid blocks
#define NSB 98           // ceil(N/2048)
#define NSHAD 8          // psum shadow copies (atomic-depth divider)
#define CMAX 16384       // max clusters supported (bitmap/pair-key bound)
#define SROWS 128        // rows per wave in segsum

__device__ __forceinline__ uint32_t f2ou(float f){
  uint32_t b = __float_as_uint(f);
  return (b & 0x80000000u) ? ~b : (b | 0x80000000u);
}

// block-wide digit selection from a completed 256-bin histogram (blockDim=256)
static __device__ __forceinline__ void sel_level(const uint32_t* hist, uint32_t& target,
                                                 uint32_t& pfx, uint32_t* sm, uint32_t* res){
  int t = threadIdx.x;
  uint32_t cnt = hist[t];
  sm[t] = cnt; __syncthreads();
  for(int off = 1; off < 256; off <<= 1){
    uint32_t y = (t + off < 256) ? sm[t + off] : 0u;
    __syncthreads(); sm[t] += y; __syncthreads();
  }
  uint32_t suffix = sm[t];            // candidates with digit >= t
  uint32_t above  = suffix - cnt;
  if(above < target && target <= suffix){ res[0] = (uint32_t)t; res[1] = target - above; }
  __syncthreads();
  pfx = (pfx << 8) | res[0];
  target = res[1];
  __syncthreads();
}

// ---- tiny ws zero (sc + 4 hist arrays + counts) ----
__global__ __launch_bounds__(256) void k_zero(uint32_t* w, uint32_t nwords){
  uint32_t gid = blockIdx.x*256 + threadIdx.x;
  for(uint32_t j = gid; j < nwords; j += gridDim.x*256) w[j] = 0u;
}

// ---- selection: 4-level 8-bit radix histograms; prior-level digits recomputed in-block ----
template<int LEVEL>
__global__ __launch_bounds__(256) void k_hist8(const float* att, uint32_t* hists, int* L){
  __shared__ uint32_t h[256];
  __shared__ uint32_t sm[256];
  __shared__ uint32_t res[2];
  h[threadIdx.x] = 0;
  if(LEVEL == 1){
    for(int i = blockIdx.x*256 + threadIdx.x; i < N_NODES; i += HB*256) L[i] = i;  // fused CC init
  }
  __syncthreads();
  uint32_t pfx = 0, target = NUM_POOL;
  #pragma unroll
  for(int l = 0; l < LEVEL-1; ++l) sel_level(hists + 256*l, target, pfx, sm, res);
  constexpr int SH1 = (LEVEL > 1) ? 8*(5-LEVEL) : 0;
  constexpr int SH2 = 8*(4-LEVEL);
  for(int e = blockIdx.x*256 + threadIdx.x; e < N_EDGES; e += HB*256){
    uint32_t u = f2ou(att[e]);
    bool ok = (LEVEL == 1) || ((u >> SH1) == pfx);
    if(ok) atomicAdd(&h[(u >> SH2) & 0xFFu], 1u);
  }
  __syncthreads();
  uint32_t c = h[threadIdx.x];
  if(c) atomicAdd(&hists[256*(LEVEL-1) + threadIdx.x], c);
}

// ---- seed: recompute full threshold in-block; pooled edges hook + worklist; ties recorded ----
__global__ __launch_bounds__(256) void k_seed(const float* att, const int* src, const int* dst,
                       const uint32_t* hists, uint32_t* sc, uint32_t* tieIdx, int* L, uint2* wl){
  __shared__ uint32_t sm[256];
  __shared__ uint32_t res[2];
  uint32_t pfx = 0, target = NUM_POOL;
  #pragma unroll
  for(int l = 0; l < 4; ++l) sel_level(hists + 256*l, target, pfx, sm, res);
  if(blockIdx.x == 0 && threadIdx.x == 0) sc[SC_NEEDEQ] = target;
  uint32_t T = pfx;
  int e = blockIdx.x*256 + threadIdx.x;
  int lane = threadIdx.x & 63;
  bool app = false; int u = 0, v = 0;
  if(e < N_EDGES){
    uint32_t ub = f2ou(att[e]);
    if(ub > T){
      u = src[e]; v = dst[e];
      if(u != v){
        int m = u < v ? u : v, hi = u ^ v ^ m;
        atomicMin(&L[hi], m);
        app = true;
      }
    } else if(ub == T){
      uint32_t p = atomicAdd(&sc[SC_TIECNT], 1u);
      if(p < TIECAP) tieIdx[p] = (uint32_t)e;
    }
  }
  unsigned long long grp = __ballot(app);
  if(grp){
    int leader = __ffsll(grp) - 1;
    uint32_t base = 0;
    if(lane == leader) base = atomicAdd(&sc[SC_WL0], (uint32_t)__popcll(grp));
    base = (uint32_t)__shfl((int)base, leader);
    if(app){
      uint32_t off = (uint32_t)__popcll(grp & ((1ull << lane) - 1ull));
      wl[base + off] = make_uint2((uint32_t)(u < v ? u : v), (uint32_t)(u > v ? u : v));
    }
  }
}
__global__ __launch_bounds__(1024) void k_tiesel(uint32_t* sc, const uint32_t* tieIdx,
                        const int* src, const int* dst, int* L, uint2* wl){
  uint32_t m = sc[SC_TIECNT]; if(m > TIECAP) m = TIECAP;
  uint32_t need = sc[SC_NEEDEQ];
  int lane = threadIdx.x & 63;
  for(uint32_t i0 = 0; i0 < m; i0 += 1024){
    uint32_t i = i0 + threadIdx.x;
    bool app = false; int u = 0, v = 0;
    if(i < m){
      uint32_t mine = tieIdx[i];
      uint32_t r = 0;
      for(uint32_t j = 0; j < m; j++) r += (tieIdx[j] < mine) ? 1u : 0u;
      if(r < need){   // stable argsort: smallest indices pooled
        u = src[mine]; v = dst[mine];
        if(u != v){ int mm = u < v ? u : v, hi = u ^ v ^ mm; atomicMin(&L[hi], mm); app = true; }
      }
    }
    unsigned long long grp = __ballot(app);
    if(grp){
      int leader = __ffsll(grp) - 1;
      uint32_t base = 0;
      if(lane == leader) base = atomicAdd(&sc[SC_WL0], (uint32_t)__popcll(grp));
      base = (uint32_t)__shfl((int)base, leader);
      if(app){
        uint32_t off = (uint32_t)__popcll(grp & ((1ull << lane) - 1ull));
        wl[base + off] = make_uint2((uint32_t)(u < v ? u : v), (uint32_t)(u > v ? u : v));
      }
    }
  }
}
// loop-free relax: 4-level chase (plain loads), one-shot hooking atomicMin, survivors re-appended.
__global__ __launch_bounds__(256) void k_relax(const uint2* wl_in, uint2* wl_out, int* L,
                       uint32_t* sc, int inSlot, int outSlot){
  uint32_t n = sc[inSlot];
  int lane = threadIdx.x & 63;
  for(uint32_t base = blockIdx.x*256u; base < n; base += gridDim.x*256u){
    uint32_t idx = base + threadIdx.x;
    bool active = idx < n;
    int lu = 0, lv = 0;
    if(active){
      uint2 ed = wl_in[idx];
      lu = L[ed.x]; lu = L[lu]; lu = L[lu]; lu = L[lu];
      lv = L[ed.y]; lv = L[lv]; lv = L[lv]; lv = L[lv];
      active = (lu != lv);
      if(active){
        int m = lu < lv ? lu : lv, hi = lu ^ lv ^ m;
        atomicMin(&L[hi], m);
      }
    }
    unsigned long long grp = __ballot(active);
    if(grp){
      int leader = __ffsll(grp) - 1;
      uint32_t b = 0;
      if(lane == leader) b = atomicAdd(&sc[outSlot], (uint32_t)__popcll(grp));
      b = (uint32_t)__shfl((int)b, leader);
      if(active){
        uint32_t off = (uint32_t)__popcll(grp & ((1ull << lane) - 1ull));
        wl_out[b + off] = make_uint2((uint32_t)(lu < lv ? lu : lv), (uint32_t)(lu > lv ? lu : lv));
      }
    }
  }
}
// pointer jumping (6-level), skipped entirely if worklist already empty
__global__ void k_jump(int* L, const uint32_t* sc, int liveSlot){
  if(sc[liveSlot] == 0) return;
  int i = blockIdx.x*256 + threadIdx.x;
  if(i >= N_NODES) return;
  int v = L[i]; v = L[v]; v = L[v]; v = L[v]; v = L[v]; v = L[v];
  L[i] = v;
}
// flatten to roots + per-block root-count reduction (2048 nodes/block)
__global__ __launch_bounds__(256) void k_flatten_reduce(int* L, uint32_t* bsums){
  uint32_t base = blockIdx.x*2048u + threadIdx.x*8u;
  uint32_t s = 0;
  #pragma unroll
  for(int k = 0; k < 8; k++){
    uint32_t i = base + k;
    if(i < N_NODES){
      int p = L[i]; int q = L[p];
      while(q != p){ p = q; q = L[p]; }
      L[i] = p;
      s += (p == (int)i) ? 1u : 0u;
    }
  }
  __shared__ uint32_t sm[256];
  sm[threadIdx.x] = s; __syncthreads();
  for(int off = 128; off > 0; off >>= 1){
    if((int)threadIdx.x < off) sm[threadIdx.x] += sm[threadIdx.x + off];
    __syncthreads();
  }
  if(threadIdx.x == 0) bsums[blockIdx.x] = sm[0];
}

// ---- 2-kernel scans. MODE 0: counts->cursor. MODE 1: popc(bitmap)->wpref (+SC_U).
//      MODE 2: rootflag(L)->rank_ (+SC_C,SC_W). apply scans bsums in-LDS itself. ----
template<int MODE>
__global__ __launch_bounds__(256) void k_scan_reduce(const uint32_t* in, uint32_t* bsums,
                       const uint32_t* sc, float* dsum, uint32_t* dcnt){
  uint32_t n = (MODE == 1) ? sc[SC_W] : N_NODES;
  if(MODE == 1){  // lazy-zero compact dual accumulators (VCNT rows >= U)
    uint32_t vc = sc[SC_VCNT];
    size_t gid = (size_t)blockIdx.x*256 + threadIdx.x, gs = (size_t)gridDim.x*256;
    for(size_t j = gid; j < (size_t)vc*FDIM; j += gs) dsum[j] = 0.f;
    for(size_t j = gid; j < vc; j += gs) dcnt[j] = 0u;
  }
  uint32_t base = blockIdx.x*2048u + threadIdx.x*8u;
  uint32_t s = 0;
  #pragma unroll
  for(int k = 0; k < 8; k++){
    uint32_t idx = base + k;
    if(idx < n){ uint32_t v = in[idx]; if(MODE == 1) v = __popc(v); s += v; }
  }
  __shared__ uint32_t sm[256];
  sm[threadIdx.x] = s; __syncthreads();
  for(int off = 128; off > 0; off >>= 1){
    if((int)threadIdx.x < off) sm[threadIdx.x] += sm[threadIdx.x + off];
    __syncthreads();
  }
  if(threadIdx.x == 0) bsums[blockIdx.x] = sm[0];
}
template<int MODE>
__global__ __launch_bounds__(256) void k_scan_apply(const uint32_t* in, const int* L,
                       const uint32_t* bsums, int nb, uint32_t* out, uint32_t* sc){
  __shared__ uint32_t bs[4096];
  __shared__ uint32_t sm[256];
  int t = threadIdx.x;
  uint32_t n = (MODE == 1) ? sc[SC_W] : N_NODES;
  uint32_t loc[16]; uint32_t ls = 0;
  #pragma unroll
  for(int k = 0; k < 16; k++){ int idx = t*16 + k; uint32_t v = (idx < nb) ? bsums[idx] : 0u; loc[k] = v; ls += v; }
  sm[t] = ls; __syncthreads();
  for(int off = 1; off < 256; off <<= 1){
    uint32_t y = (t >= off) ? sm[t - off] : 0u;
    __syncthreads(); sm[t] += y; __syncthreads();
  }
  uint32_t total = sm[255];
  uint32_t run = sm[t] - ls;
  #pragma unroll
  for(int k = 0; k < 16; k++){ bs[t*16 + k] = run; run += loc[k]; }
  __syncthreads();
  uint32_t blockbase = bs[blockIdx.x];
  __syncthreads();
  uint32_t base = blockIdx.x*2048u + t*8u;
  uint32_t xs[8]; uint32_t ts2 = 0;
  #pragma unroll
  for(int k = 0; k < 8; k++){
    uint32_t idx = base + k; uint32_t v = 0;
    if(idx < n){
      if(MODE == 2) v = (L[idx] == (int)idx) ? 1u : 0u;
      else { v = in[idx]; if(MODE == 1) v = __popc(v); }
    }
    xs[k] = v; ts2 += v;
  }
  sm[t] = ts2; __syncthreads();
  for(int off = 1; off < 256; off <<= 1){
    uint32_t y = (t >= off) ? sm[t - off] : 0u;
    __syncthreads(); sm[t] += y; __syncthreads();
  }
  uint32_t run2 = blockbase + sm[t] - ts2;
  #pragma unroll
  for(int k = 0; k < 8; k++){ uint32_t idx = base + k; if(idx < n) out[idx] = run2; run2 += xs[k]; }
  if(blockIdx.x == 0 && t == 0){
    if(MODE == 2){ sc[SC_C] = total; uint64_t cc = (uint64_t)total*(uint64_t)total; sc[SC_W] = (uint32_t)((cc + 31ull) >> 5); }
    if(MODE == 1){ sc[SC_U] = total; }
  }
}

// ---- cluster ids + wave-agg counts + lazy zero of psumS[0..NSHAD*C*F) and bitmap[0..W) ----
__global__ __launch_bounds__(256) void k_cluster_counts(const int* L, const uint32_t* rank_,
                       int* cluster_i, float* outC, uint32_t* counts, float* psumS,
                       uint32_t* bitmap, const uint32_t* sc){
  uint32_t C = sc[SC_C], W = sc[SC_W];
  uint32_t gid = blockIdx.x*256 + threadIdx.x, gs = gridDim.x*256;
  for(size_t j = gid; j < (size_t)NSHAD*C*FDIM; j += gs) psumS[j] = 0.f;
  for(uint32_t j = gid; j < W; j += gs) bitmap[j] = 0u;
  int i = (int)gid;
  int lane = threadIdx.x & 63;
  int c = -1;
  if(i < N_NODES){
    c = (int)rank_[L[i]];
    cluster_i[i] = c;
    outC[i] = (float)c;
  }
  unsigned long long remaining = __ballot(i < N_NODES);
  while(remaining){
    int leader = __ffsll(remaining) - 1;
    int lc = __shfl(c, leader);
    unsigned long long grp = __ballot(c == lc) & remaining;
    if(lane == leader) atomicAdd(&counts[lc], (uint32_t)__popcll(grp));
    remaining &= ~grp;
  }
}
__global__ void k_scatter(const int* cluster_i, uint32_t* cursor, uint32_t* order){
  int i = blockIdx.x*256 + threadIdx.x;
  int lane = threadIdx.x & 63;
  int c = (i < N_NODES) ? cluster_i[i] : -1;
  unsigned long long remaining = __ballot(i < N_NODES);
  while(remaining){
    int leader = __ffsll(remaining) - 1;
    int lc = __shfl(c, leader);
    unsigned long long grp = __ballot(c == lc) & remaining;
    int b = 0;
    if(lane == leader) b = (int)atomicAdd(&cursor[lc], (uint32_t)__popcll(grp));
    b = __shfl(b, leader);
    if((grp >> lane) & 1ull){
      uint32_t sub = (uint32_t)__popcll(grp & ((1ull << lane) - 1ull));
      order[(uint32_t)b + sub] = (uint32_t)i;
    }
    remaining &= ~grp;
  }
}

// ---- segmented mean: 128 rows/wave, shfl-broadcast order/cluster, 8-shadow flush ----
__global__ __launch_bounds__(256) void k_segsum(const float* px, const uint32_t* order,
        const int* cluster_i, float* psumS, const uint32_t* sc){
  int wave = (int)((blockIdx.x*256u + threadIdx.x) >> 6);
  int lane = threadIdx.x & 63;
  int start = wave * SROWS;
  if(start >= N_NODES) return;
  int cnt = N_NODES - start; if(cnt > SROWS) cnt = SROWS;
  size_t shadBase = (size_t)(wave & (NSHAD-1)) * (size_t)sc[SC_C] * FDIM;
  uint32_t ord0 = 0, ord1 = 0; int c0 = -1, c1 = -1;
  if(lane < cnt){ ord0 = order[start + lane]; c0 = cluster_i[ord0]; }
  if(64 + lane < cnt){ ord1 = order[start + 64 + lane]; c1 = cluster_i[ord1]; }
  float ax = 0.f, ay = 0.f; int cur = -1;
  for(int r = 0; r < cnt; r++){
    uint32_t i; int c;
    if(r < 64){ i = (uint32_t)__shfl((int)ord0, r); c = __shfl(c0, r); }
    else      { i = (uint32_t)__shfl((int)ord1, r - 64); c = __shfl(c1, r - 64); }
    if(c != cur){
      if(cur >= 0){
        atomicAdd(&psumS[shadBase + (size_t)cur*FDIM + 2*lane], ax);
        atomicAdd(&psumS[shadBase + (size_t)cur*FDIM + 2*lane + 1], ay);
      }
      cur = c; ax = 0.f; ay = 0.f;
    }
    float2 v = ((const float2*)(px + (size_t)i*FDIM))[lane];
    ax += v.x; ay += v.y;
  }
  if(cur >= 0){
    atomicAdd(&psumS[shadBase + (size_t)cur*FDIM + 2*lane], ax);
    atomicAdd(&psumS[shadBase + (size_t)cur*FDIM + 2*lane + 1], ay);
  }
}

// ---- edges: rebuilt edge index + pair-key bitmap; one count atomic per block ----
__global__ __launch_bounds__(256) void k_edges(const int* src, const int* dst,
        const int* cluster_i, uint32_t* sc, float* outE, uint32_t* kc, uint32_t* bitmap){
  __shared__ uint32_t wsum[4];
  int e = blockIdx.x*256 + threadIdx.x;
  int lane = threadIdx.x & 63;
  int wv = threadIdx.x >> 6;
  bool val = false;
  if(e < N_EDGES){
    int cu = cluster_i[src[e]];
    int cv = cluster_i[dst[e]];
    val = (cu != cv);
    outE[e] = val ? (float)cu : -1.0f;
    outE[N_EDGES + e] = val ? (float)cv : -1.0f;
    if(val){
      int a = cu < cv ? cu : cv, b = cu < cv ? cv : cu;
      uint32_t C = sc[SC_C];
      uint32_t key = (uint32_t)a * C + (uint32_t)b;
      kc[e] = key;
      atomicOr(&bitmap[key >> 5], 1u << (key & 31u));
    } else {
      kc[e] = 0xFFFFFFFFu;
    }
  }
  unsigned long long grp = __ballot(val);
  if(lane == 0) wsum[wv] = (uint32_t)__popcll(grp);
  __syncthreads();
  if(threadIdx.x == 0){
    uint32_t s = wsum[0] + wsum[1] + wsum[2] + wsum[3];
    if(s) atomicAdd(&sc[SC_VCNT], s);   // fire-and-forget (upper bound for dsum zeroing)
  }
}

// ---- dual accumulate: 64 edges/wave, ballot + shfl-broadcast rank ----
__global__ __launch_bounds__(256) void k_dualacc(const float* dx, const uint32_t* kc,
                          const uint32_t* bitmap, const uint32_t* wpref,
                          float* dsum, uint32_t* dcnt){
  int wave = (int)((blockIdx.x*256u + threadIdx.x) >> 6);
  int lane = threadIdx.x & 63;
  int base = wave * 64;
  if(base >= N_EDGES) return;
  int e = base + lane;
  uint32_t key = (e < N_EDGES) ? kc[e] : 0xFFFFFFFFu;
  bool val = (key != 0xFFFFFFFFu);
  uint32_t r = 0;
  if(val){
    uint32_t wi = key >> 5, bi = key & 31u;
    r = wpref[wi] + __popc(bitmap[wi] & ((1u << bi) - 1u));
  }
  unsigned long long m = __ballot(val);
  while(m){
    int b = __ffsll(m) - 1;
    m &= m - 1;
    uint32_t ee = (uint32_t)(base + b);
    uint32_t rr = (uint32_t)__shfl((int)r, b);
    float2 v = ((const float2*)(dx + (size_t)ee*FDIM))[lane];
    atomicAdd(&dsum[(size_t)rr*FDIM + 2*lane], v.x);
    atomicAdd(&dsum[(size_t)rr*FDIM + 2*lane + 1], v.y);
    if(lane == 0) atomicAdd(&dcnt[rr], 1u);
  }
}
// ---- stream the full output region: shadow-summed means for live rows, zeros elsewhere ----
__global__ __launch_bounds__(256) void k_finalize(const float4* psumS, const uint32_t* counts,
        const float4* dsum, const uint32_t* dcnt, const uint32_t* sc, float4* out4){
  uint32_t C = sc[SC_C], U = sc[SC_U];
  size_t cs = (size_t)C * (FDIM/4);          // shadow stride in float4
  size_t gid = (size_t)blockIdx.x*256 + threadIdx.x;
  size_t gs = (size_t)gridDim.x*256;
  const size_t NP4 = (size_t)N_NODES*(FDIM/4);
  const size_t TOT4 = (size_t)(N_NODES + N_EDGES)*(FDIM/4);
  for(size_t j = gid; j < TOT4; j += gs){
    float4 v = make_float4(0.f,0.f,0.f,0.f);
    if(j < NP4){
      uint32_t r = (uint32_t)(j >> 5);
      if(r < C){
        v = psumS[j];
        #pragma unroll
        for(int s = 1; s < NSHAD; s++){
          float4 t = psumS[(size_t)s*cs + j];
          v.x += t.x; v.y += t.y; v.z += t.z; v.w += t.w;
        }
        float fc = (float)counts[r];
        v.x /= fc; v.y /= fc; v.z /= fc; v.w /= fc;
      }
    } else {
      size_t dj = j - NP4;
      uint32_t r = (uint32_t)(dj >> 5);
      if(r < U){
        v = dsum[dj];
        float fc = (float)dcnt[r];
        v.x /= fc; v.y /= fc; v.z /= fc; v.w /= fc;
      }
    }
    out4[j] = v;
  }
}

extern "C" void kernel_launch(void* const* d_in, const int* in_sizes, int n_in,
                              void* d_out, int out_size, void* d_ws, size_t ws_size,
                              hipStream_t stream){
  (void)in_sizes; (void)n_in; (void)out_size;
  const float* primal_x = (const float*)d_in[0];
  const float* dual_x   = (const float*)d_in[1];
  const float* att      = (const float*)d_in[2];
  const int*   pei      = (const int*)d_in[3];
  const int* src = pei;
  const int* dst = pei + N_EDGES;

  float* out  = (float*)d_out;
  float* outE = out + (size_t)(N_NODES + N_EDGES)*FDIM;   // (2, E)
  float* outC = outE + (size_t)2*N_EDGES;                 // (N,)

  uint32_t* w = (uint32_t*)d_ws;
  size_t words_avail = ws_size / 4;
  const size_t PSUMW = (size_t)NSHAD*CMAX*FDIM;            // 16.8M words
  const size_t FIXED = 64 + 1024 + (size_t)N_NODES
                     + TIECAP + 5*(size_t)N_NODES + 4*(size_t)WLCAP
                     + (size_t)N_EDGES + (size_t)N_EDGES   // kc + dcnt
                     + 4096
                     + PSUMW + (size_t)N_EDGES*FDIM;       // psumS + dsum
  size_t wcap = (words_avail > FIXED) ? (words_avail - FIXED)/2 : 4;
  if(wcap > 8388608) wcap = 8388608;   // supports C up to 16384
  wcap &= ~(size_t)3;

  size_t o = 0;
  uint32_t* sc     = w;               o += 64;
  uint32_t* hists  = w + o;           o += 1024;          // 4 x 256
  uint32_t* counts = w + o;           o += N_NODES;
  size_t zero_words = o;                                   // zeroed per call
  uint32_t* tieIdx = w + o;           o += TIECAP;
  int* labels      = (int*)(w + o);   o += N_NODES;
  uint32_t* rank_  = w + o;           o += N_NODES;
  uint32_t* cursor = w + o;           o += N_NODES;
  int* cluster_i   = (int*)(w + o);   o += N_NODES;
  uint32_t* order  = w + o;           o += N_NODES;
  uint2* wl0       = (uint2*)(w + o); o += 2*(size_t)WLCAP;
  uint2* wl1       = (uint2*)(w + o); o += 2*(size_t)WLCAP;
  uint32_t* kc     = w + o;           o += N_EDGES;
  uint32_t* dcnt   = w + o;           o += N_EDGES;
  uint32_t* bsums  = w + o;           o += 4096;
  float* psumS     = (float*)(w + o); o += PSUMW;
  float* dsum      = (float*)(w + o); o += (size_t)N_EDGES*FDIM;
  uint32_t* bitmap = w + o;           o += wcap;
  uint32_t* wpref  = w + o;           o += wcap;

  const int EB  = (N_EDGES + 255)/256;
  const int NB  = (N_NODES + 255)/256;
  const int SGB = (N_NODES + SROWS*4 - 1)/(SROWS*4);   // 128 rows/wave, 4 waves/block = 391
  const int WSB = (int)((wcap + 2047)/2048);           // <= 4096

  k_zero<<<64,256,0,stream>>>(w, (uint32_t)zero_words);
  // selection: 4 hist levels (prior digits recomputed in-block; L init fused in L1)
  k_hist8<1><<<HB,256,0,stream>>>(att, hists, labels);
  k_hist8<2><<<HB,256,0,stream>>>(att, hists, labels);
  k_hist8<3><<<HB,256,0,stream>>>(att, hists, labels);
  k_hist8<4><<<HB,256,0,stream>>>(att, hists, labels);
  // CC: seed + tie handling + relax/jump ladder (per-round counter slots, never reset)
  k_seed<<<EB,256,0,stream>>>(att, src, dst, hists, sc, tieIdx, labels, wl0);
  k_tiesel<<<1,1024,0,stream>>>(sc, tieIdx, src, dst, labels, wl0);
  for(int r = 1; r <= 8; ++r){
    uint2* win  = (r & 1) ? wl0 : wl1;
    uint2* wout = (r & 1) ? wl1 : wl0;
    k_relax<<<1024,256,0,stream>>>(win, wout, labels, sc, SC_WL0 + r - 1, SC_WL0 + r);
    if(r <= 3) k_jump<<<NB,256,0,stream>>>(labels, sc, SC_WL0 + r);
  }
  k_flatten_reduce<<<NSB,256,0,stream>>>(labels, bsums);
  k_scan_apply<2><<<NSB,256,0,stream>>>(counts, labels, bsums, NSB, rank_, sc);   // -> rank_, SC_C, SC_W
  k_cluster_counts<<<NB,256,0,stream>>>(labels, rank_, cluster_i, outC, counts, psumS, bitmap, sc);
  k_scan_reduce<0><<<NSB,256,0,stream>>>(counts, bsums, sc, dsum, dcnt);
  k_scan_apply<0><<<NSB,256,0,stream>>>(counts, labels, bsums, NSB, cursor, sc);  // -> cursor
  k_scatter<<<NB,256,0,stream>>>(cluster_i, cursor, order);
  k_segsum<<<SGB,256,0,stream>>>(primal_x, order, cluster_i, psumS, sc);
  k_edges<<<EB,256,0,stream>>>(src, dst, cluster_i, sc, outE, kc, bitmap);
  k_scan_reduce<1><<<WSB,256,0,stream>>>(bitmap, bsums, sc, dsum, dcnt);          // + lazy zero dsum/dcnt
  k_scan_apply<1><<<WSB,256,0,stream>>>(bitmap, labels, bsums, WSB, wpref, sc);   // -> wpref, SC_U
  k_dualacc<<<EB,256,0,stream>>>(dual_x, kc, bitmap, wpref, dsum, dcnt);
  k_finalize<<<2048,256,0,stream>>>((const float4*)psumS, counts, (const float4*)dsum,
                                    dcnt, sc, (float4*)out);
}

// Round 11
// 704.941 us; speedup vs baseline: 1.3276x; 1.0278x over previous
//
#include <hip/hip_runtime.h>
#include <stdint.h>

// DualPrimalEdgePooling on MI355X — atomic-depth-limited pipeline (29 dispatches).
// radix-select -> worklist min-label CC -> fused flatten/scan/cluster ->
// 16-shadow counting-sort scatter -> 128-rows/wave shfl-broadcast segmented
// mean into 8 shadow accumulators (fused with edges+bitmap) -> popcount-prefix
// dual ranking -> finalize streams output.

#define N_NODES 200000
#define N_EDGES 600000
#define FDIM 128
#define NUM_POOL 300000u  // = E - NUM_KEEP

#define SC_NEEDEQ 3
#define SC_TIECNT 4
#define SC_C 5
#define SC_W 6
#define SC_U 7
#define SC_VCNT 8
#define SC_WL0 16        // per-round worklist counters: slots 16..24 (never reset)
#define TIECAP 4096
#define WLCAP 300800
#define HB 256           // hist grid blocks
#define NSB 98           // ceil(N/2048)
#define NSHAD 8          // psum shadow copies (atomic-depth divider)
#define NSHAD2 16        // scatter cursor shadows
#define CMAX 16384       // max clusters supported (bitmap/pair-key bound)
#define SROWS 128        // rows per wave in segsum
#define SGB 391          // ceil(N/(SROWS*4)) segsum blocks
#define CS2B 128         // scan blocks for counts2 (CMAX*16/2048)

__device__ __forceinline__ uint32_t f2ou(float f){
  uint32_t b = __float_as_uint(f);
  return (b & 0x80000000u) ? ~b : (b | 0x80000000u);
}

// block-wide digit selection from a completed 256-bin histogram (blockDim=256)
static __device__ __forceinline__ void sel_level(const uint32_t* hist, uint32_t& target,
                                                 uint32_t& pfx, uint32_t* sm, uint32_t* res){
  int t = threadIdx.x;
  uint32_t cnt = hist[t];
  sm[t] = cnt; __syncthreads();
  for(int off = 1; off < 256; off <<= 1){
    uint32_t y = (t + off < 256) ? sm[t + off] : 0u;
    __syncthreads(); sm[t] += y; __syncthreads();
  }
  uint32_t suffix = sm[t];            // candidates with digit >= t
  uint32_t above  = suffix - cnt;
  if(above < target && target <= suffix){ res[0] = (uint32_t)t; res[1] = target - above; }
  __syncthreads();
  pfx = (pfx << 8) | res[0];
  target = res[1];
  __syncthreads();
}

// ---- tiny ws zero (sc + hists + counts + counts2) ----
__global__ __launch_bounds__(256) void k_zero(uint32_t* w, uint32_t nwords){
  uint32_t gid = blockIdx.x*256 + threadIdx.x;
  for(uint32_t j = gid; j < nwords; j += gridDim.x*256) w[j] = 0u;
}

// ---- selection: 4-level 8-bit radix histograms; prior-level digits recomputed in-block ----
template<int LEVEL>
__global__ __launch_bounds__(256) void k_hist8(const float* att, uint32_t* hists, int* L){
  __shared__ uint32_t h[256];
  __shared__ uint32_t sm[256];
  __shared__ uint32_t res[2];
  h[threadIdx.x] = 0;
  if(LEVEL == 1){
    for(int i = blockIdx.x*256 + threadIdx.x; i < N_NODES; i += HB*256) L[i] = i;  // fused CC init
  }
  __syncthreads();
  uint32_t pfx = 0, target = NUM_POOL;
  #pragma unroll
  for(int l = 0; l < LEVEL-1; ++l) sel_level(hists + 256*l, target, pfx, sm, res);
  constexpr int SH1 = (LEVEL > 1) ? 8*(5-LEVEL) : 0;
  constexpr int SH2 = 8*(4-LEVEL);
  for(int e = blockIdx.x*256 + threadIdx.x; e < N_EDGES; e += HB*256){
    uint32_t u = f2ou(att[e]);
    bool ok = (LEVEL == 1) || ((u >> SH1) == pfx);
    if(ok) atomicAdd(&h[(u >> SH2) & 0xFFu], 1u);
  }
  __syncthreads();
  uint32_t c = h[threadIdx.x];
  if(c) atomicAdd(&hists[256*(LEVEL-1) + threadIdx.x], c);
}

// ---- seed: recompute full threshold in-block; pooled edges hook + worklist; ties recorded ----
__global__ __launch_bounds__(256) void k_seed(const float* att, const int* src, const int* dst,
                       const uint32_t* hists, uint32_t* sc, uint32_t* tieIdx, int* L, uint2* wl){
  __shared__ uint32_t sm[256];
  __shared__ uint32_t res[2];
  uint32_t pfx = 0, target = NUM_POOL;
  #pragma unroll
  for(int l = 0; l < 4; ++l) sel_level(hists + 256*l, target, pfx, sm, res);
  if(blockIdx.x == 0 && threadIdx.x == 0) sc[SC_NEEDEQ] = target;
  uint32_t T = pfx;
  int e = blockIdx.x*256 + threadIdx.x;
  int lane = threadIdx.x & 63;
  bool app = false; int u = 0, v = 0;
  if(e < N_EDGES){
    uint32_t ub = f2ou(att[e]);
    if(ub > T){
      u = src[e]; v = dst[e];
      if(u != v){
        int m = u < v ? u : v, hi = u ^ v ^ m;
        atomicMin(&L[hi], m);
        app = true;
      }
    } else if(ub == T){
      uint32_t p = atomicAdd(&sc[SC_TIECNT], 1u);
      if(p < TIECAP) tieIdx[p] = (uint32_t)e;
    }
  }
  unsigned long long grp = __ballot(app);
  if(grp){
    int leader = __ffsll(grp) - 1;
    uint32_t base = 0;
    if(lane == leader) base = atomicAdd(&sc[SC_WL0], (uint32_t)__popcll(grp));
    base = (uint32_t)__shfl((int)base, leader);
    if(app){
      uint32_t off = (uint32_t)__popcll(grp & ((1ull << lane) - 1ull));
      wl[base + off] = make_uint2((uint32_t)(u < v ? u : v), (uint32_t)(u > v ? u : v));
    }
  }
}
__global__ __launch_bounds__(1024) void k_tiesel(uint32_t* sc, const uint32_t* tieIdx,
                        const int* src, const int* dst, int* L, uint2* wl){
  uint32_t m = sc[SC_TIECNT]; if(m > TIECAP) m = TIECAP;
  uint32_t need = sc[SC_NEEDEQ];
  int lane = threadIdx.x & 63;
  for(uint32_t i0 = 0; i0 < m; i0 += 1024){
    uint32_t i = i0 + threadIdx.x;
    bool app = false; int u = 0, v = 0;
    if(i < m){
      uint32_t mine = tieIdx[i];
      uint32_t r = 0;
      for(uint32_t j = 0; j < m; j++) r += (tieIdx[j] < mine) ? 1u : 0u;
      if(r < need){   // stable argsort: smallest indices pooled
        u = src[mine]; v = dst[mine];
        if(u != v){ int mm = u < v ? u : v, hi = u ^ v ^ mm; atomicMin(&L[hi], mm); app = true; }
      }
    }
    unsigned long long grp = __ballot(app);
    if(grp){
      int leader = __ffsll(grp) - 1;
      uint32_t base = 0;
      if(lane == leader) base = atomicAdd(&sc[SC_WL0], (uint32_t)__popcll(grp));
      base = (uint32_t)__shfl((int)base, leader);
      if(app){
        uint32_t off = (uint32_t)__popcll(grp & ((1ull << lane) - 1ull));
        wl[base + off] = make_uint2((uint32_t)(u < v ? u : v), (uint32_t)(u > v ? u : v));
      }
    }
  }
}
// loop-free relax: 4-level chase (plain loads), one-shot hooking atomicMin, survivors re-appended.
__global__ __launch_bounds__(256) void k_relax(const uint2* wl_in, uint2* wl_out, int* L,
                       uint32_t* sc, int inSlot, int outSlot){
  uint32_t n = sc[inSlot];
  int lane = threadIdx.x & 63;
  for(uint32_t base = blockIdx.x*256u; base < n; base += gridDim.x*256u){
    uint32_t idx = base + threadIdx.x;
    bool active = idx < n;
    int lu = 0, lv = 0;
    if(active){
      uint2 ed = wl_in[idx];
      lu = L[ed.x]; lu = L[lu]; lu = L[lu]; lu = L[lu];
      lv = L[ed.y]; lv = L[lv]; lv = L[lv]; lv = L[lv];
      active = (lu != lv);
      if(active){
        int m = lu < lv ? lu : lv, hi = lu ^ lv ^ m;
        atomicMin(&L[hi], m);
      }
    }
    unsigned long long grp = __ballot(active);
    if(grp){
      int leader = __ffsll(grp) - 1;
      uint32_t b = 0;
      if(lane == leader) b = atomicAdd(&sc[outSlot], (uint32_t)__popcll(grp));
      b = (uint32_t)__shfl((int)b, leader);
      if(active){
        uint32_t off = (uint32_t)__popcll(grp & ((1ull << lane) - 1ull));
        wl_out[b + off] = make_uint2((uint32_t)(lu < lv ? lu : lv), (uint32_t)(lu > lv ? lu : lv));
      }
    }
  }
}
// pointer jumping (6-level), skipped entirely if worklist already empty
__global__ void k_jump(int* L, const uint32_t* sc, int liveSlot){
  if(sc[liveSlot] == 0) return;
  int i = blockIdx.x*256 + threadIdx.x;
  if(i >= N_NODES) return;
  int v = L[i]; v = L[v]; v = L[v]; v = L[v]; v = L[v]; v = L[v];
  L[i] = v;
}
// flatten to roots + per-block root-count reduction (2048 nodes/block)
__global__ __launch_bounds__(256) void k_flatten_reduce(int* L, uint32_t* bsums){
  uint32_t base = blockIdx.x*2048u + threadIdx.x*8u;
  uint32_t s = 0;
  #pragma unroll
  for(int k = 0; k < 8; k++){
    uint32_t i = base + k;
    if(i < N_NODES){
      int p = L[i]; int q = L[p];
      while(q != p){ p = q; q = L[p]; }
      L[i] = p;
      s += (p == (int)i) ? 1u : 0u;
    }
  }
  __shared__ uint32_t sm[256];
  sm[threadIdx.x] = s; __syncthreads();
  for(int off = 128; off > 0; off >>= 1){
    if((int)threadIdx.x < off) sm[threadIdx.x] += sm[threadIdx.x + off];
    __syncthreads();
  }
  if(threadIdx.x == 0) bsums[blockIdx.x] = sm[0];
}

// ---- 2-kernel scans. MODE 1: popc(bitmap)->wpref (+SC_U). MODE 2: rootflag(L)->rank_
//      (+SC_C,SC_W). MODE 3: counts2->cursor2 (n = C*NSHAD2). apply scans bsums in-LDS. ----
template<int MODE>
__device__ __forceinline__ uint32_t scan_n(const uint32_t* sc){
  if(MODE == 1) return sc[SC_W];
  if(MODE == 3) return sc[SC_C]*NSHAD2;
  return N_NODES;
}
template<int MODE>
__global__ __launch_bounds__(256) void k_scan_reduce(const uint32_t* in, uint32_t* bsums,
                       const uint32_t* sc, float* dsum, uint32_t* dcnt){
  uint32_t n = scan_n<MODE>(sc);
  if(MODE == 1){  // lazy-zero compact dual accumulators (VCNT rows >= U)
    uint32_t vc = sc[SC_VCNT];
    size_t gid = (size_t)blockIdx.x*256 + threadIdx.x, gs = (size_t)gridDim.x*256;
    for(size_t j = gid; j < (size_t)vc*FDIM; j += gs) dsum[j] = 0.f;
    for(size_t j = gid; j < vc; j += gs) dcnt[j] = 0u;
  }
  uint32_t base = blockIdx.x*2048u + threadIdx.x*8u;
  uint32_t s = 0;
  #pragma unroll
  for(int k = 0; k < 8; k++){
    uint32_t idx = base + k;
    if(idx < n){ uint32_t v = in[idx]; if(MODE == 1) v = __popc(v); s += v; }
  }
  __shared__ uint32_t sm[256];
  sm[threadIdx.x] = s; __syncthreads();
  for(int off = 128; off > 0; off >>= 1){
    if((int)threadIdx.x < off) sm[threadIdx.x] += sm[threadIdx.x + off];
    __syncthreads();
  }
  if(threadIdx.x == 0) bsums[blockIdx.x] = sm[0];
}
template<int MODE>
__global__ __launch_bounds__(256) void k_scan_apply(const uint32_t* in, const int* L,
                       const uint32_t* bsums, int nb, uint32_t* out, uint32_t* sc){
  __shared__ uint32_t bs[4096];
  __shared__ uint32_t sm[256];
  int t = threadIdx.x;
  uint32_t n = scan_n<MODE>(sc);
  uint32_t loc[16]; uint32_t ls = 0;
  #pragma unroll
  for(int k = 0; k < 16; k++){ int idx = t*16 + k; uint32_t v = (idx < nb) ? bsums[idx] : 0u; loc[k] = v; ls += v; }
  sm[t] = ls; __syncthreads();
  for(int off = 1; off < 256; off <<= 1){
    uint32_t y = (t >= off) ? sm[t - off] : 0u;
    __syncthreads(); sm[t] += y; __syncthreads();
  }
  uint32_t total = sm[255];
  uint32_t run = sm[t] - ls;
  #pragma unroll
  for(int k = 0; k < 16; k++){ bs[t*16 + k] = run; run += loc[k]; }
  __syncthreads();
  uint32_t blockbase = bs[blockIdx.x];
  __syncthreads();
  uint32_t base = blockIdx.x*2048u + t*8u;
  uint32_t xs[8]; uint32_t ts2 = 0;
  #pragma unroll
  for(int k = 0; k < 8; k++){
    uint32_t idx = base + k; uint32_t v = 0;
    if(idx < n){
      if(MODE == 2) v = (L[idx] == (int)idx) ? 1u : 0u;
      else { v = in[idx]; if(MODE == 1) v = __popc(v); }
    }
    xs[k] = v; ts2 += v;
  }
  sm[t] = ts2; __syncthreads();
  for(int off = 1; off < 256; off <<= 1){
    uint32_t y = (t >= off) ? sm[t - off] : 0u;
    __syncthreads(); sm[t] += y; __syncthreads();
  }
  uint32_t run2 = blockbase + sm[t] - ts2;
  #pragma unroll
  for(int k = 0; k < 8; k++){ uint32_t idx = base + k; if(idx < n) out[idx] = run2; run2 += xs[k]; }
  if(blockIdx.x == 0 && t == 0){
    if(MODE == 2){ sc[SC_C] = total; uint64_t cc = (uint64_t)total*(uint64_t)total; sc[SC_W] = (uint32_t)((cc + 31ull) >> 5); }
    if(MODE == 1){ sc[SC_U] = total; }
  }
}

// ---- cluster ids + wave-agg counts (total + per-shadow) + lazy zero psumS/bitmap ----
__global__ __launch_bounds__(256) void k_cluster_counts(const int* L, const uint32_t* rank_,
                       int* cluster_i, float* outC, uint32_t* counts, uint32_t* counts2,
                       float* psumS, uint32_t* bitmap, const uint32_t* sc){
  uint32_t C = sc[SC_C], W = sc[SC_W];
  uint32_t gid = blockIdx.x*256 + threadIdx.x, gs = gridDim.x*256;
  for(size_t j = gid; j < (size_t)NSHAD*C*FDIM; j += gs) psumS[j] = 0.f;
  for(uint32_t j = gid; j < W; j += gs) bitmap[j] = 0u;
  int i = (int)gid;
  int lane = threadIdx.x & 63;
  int sh = (int)((gid >> 6) & (NSHAD2-1));
  int c = -1;
  if(i < N_NODES){
    c = (int)rank_[L[i]];
    cluster_i[i] = c;
    outC[i] = (float)c;
  }
  unsigned long long remaining = __ballot(i < N_NODES);
  while(remaining){
    int leader = __ffsll(remaining) - 1;
    int lc = __shfl(c, leader);
    unsigned long long grp = __ballot(c == lc) & remaining;
    if(lane == leader){
      uint32_t cnt = (uint32_t)__popcll(grp);
      atomicAdd(&counts[lc], cnt);                       // fire-and-forget (means)
      atomicAdd(&counts2[lc*NSHAD2 + sh], cnt);          // per-shadow capacity
    }
    remaining &= ~grp;
  }
}
// scatter via 16-shadow cursors: same grid geometry as k_cluster_counts => exact capacities
__global__ void k_scatter(const int* cluster_i, uint32_t* cursor2, uint32_t* order){
  uint32_t gid = blockIdx.x*256 + threadIdx.x;
  int i = (int)gid;
  int lane = threadIdx.x & 63;
  int sh = (int)((gid >> 6) & (NSHAD2-1));
  int c = (i < N_NODES) ? cluster_i[i] : -1;
  unsigned long long remaining = __ballot(i < N_NODES);
  while(remaining){
    int leader = __ffsll(remaining) - 1;
    int lc = __shfl(c, leader);
    unsigned long long grp = __ballot(c == lc) & remaining;
    int b = 0;
    if(lane == leader) b = (int)atomicAdd(&cursor2[lc*NSHAD2 + sh], (uint32_t)__popcll(grp));
    b = __shfl(b, leader);
    if((grp >> lane) & 1ull){
      uint32_t sub = (uint32_t)__popcll(grp & ((1ull << lane) - 1ull));
      order[(uint32_t)b + sub] = (uint32_t)i;
    }
    remaining &= ~grp;
  }
}

// ---- fused: segmented mean into 8-shadow psum (blocks < SGB) | edges+bitmap (rest) ----
__global__ __launch_bounds__(256) void k_seg_edges(const float* px, const uint32_t* order,
        const int* cluster_i, float* psumS, const int* src, const int* dst, uint32_t* sc,
        float* outE, uint32_t* kc, uint32_t* bitmap){
  if(blockIdx.x < SGB){
    int wave = (int)((blockIdx.x*256u + threadIdx.x) >> 6);
    int lane = threadIdx.x & 63;
    int start = wave * SROWS;
    if(start >= N_NODES) return;
    int cnt = N_NODES - start; if(cnt > SROWS) cnt = SROWS;
    size_t shadBase = (size_t)(wave & (NSHAD-1)) * (size_t)sc[SC_C] * FDIM;
    uint32_t ord0 = 0, ord1 = 0; int c0 = -1, c1 = -1;
    if(lane < cnt){ ord0 = order[start + lane]; c0 = cluster_i[ord0]; }
    if(64 + lane < cnt){ ord1 = order[start + 64 + lane]; c1 = cluster_i[ord1]; }
    float ax = 0.f, ay = 0.f; int cur = -1;
    for(int r = 0; r < cnt; r++){
      uint32_t i; int c;
      if(r < 64){ i = (uint32_t)__shfl((int)ord0, r); c = __shfl(c0, r); }
      else      { i = (uint32_t)__shfl((int)ord1, r - 64); c = __shfl(c1, r - 64); }
      if(c != cur){
        if(cur >= 0){
          atomicAdd(&psumS[shadBase + (size_t)cur*FDIM + 2*lane], ax);
          atomicAdd(&psumS[shadBase + (size_t)cur*FDIM + 2*lane + 1], ay);
        }
        cur = c; ax = 0.f; ay = 0.f;
      }
      float2 v = ((const float2*)(px + (size_t)i*FDIM))[lane];
      ax += v.x; ay += v.y;
    }
    if(cur >= 0){
      atomicAdd(&psumS[shadBase + (size_t)cur*FDIM + 2*lane], ax);
      atomicAdd(&psumS[shadBase + (size_t)cur*FDIM + 2*lane + 1], ay);
    }
  } else {
    __shared__ uint32_t wsum[4];
    int e = (blockIdx.x - SGB)*256 + threadIdx.x;
    int lane = threadIdx.x & 63;
    int wv = threadIdx.x >> 6;
    bool val = false;
    if(e < N_EDGES){
      int cu = cluster_i[src[e]];
      int cv = cluster_i[dst[e]];
      val = (cu != cv);
      outE[e] = val ? (float)cu : -1.0f;
      outE[N_EDGES + e] = val ? (float)cv : -1.0f;
      if(val){
        int a = cu < cv ? cu : cv, b = cu < cv ? cv : cu;
        uint32_t C = sc[SC_C];
        uint32_t key = (uint32_t)a * C + (uint32_t)b;
        kc[e] = key;
        atomicOr(&bitmap[key >> 5], 1u << (key & 31u));
      } else {
        kc[e] = 0xFFFFFFFFu;
      }
    }
    unsigned long long grp = __ballot(val);
    if(lane == 0) wsum[wv] = (uint32_t)__popcll(grp);
    __syncthreads();
    if(threadIdx.x == 0){
      uint32_t s = wsum[0] + wsum[1] + wsum[2] + wsum[3];
      if(s) atomicAdd(&sc[SC_VCNT], s);   // fire-and-forget (upper bound for dsum zeroing)
    }
  }
}

// ---- dual accumulate: 64 edges/wave, ballot + shfl-broadcast rank ----
__global__ __launch_bounds__(256) void k_dualacc(const float* dx, const uint32_t* kc,
                          const uint32_t* bitmap, const uint32_t* wpref,
                          float* dsum, uint32_t* dcnt){
  int wave = (int)((blockIdx.x*256u + threadIdx.x) >> 6);
  int lane = threadIdx.x & 63;
  int base = wave * 64;
  if(base >= N_EDGES) return;
  int e = base + lane;
  uint32_t key = (e < N_EDGES) ? kc[e] : 0xFFFFFFFFu;
  bool val = (key != 0xFFFFFFFFu);
  uint32_t r = 0;
  if(val){
    uint32_t wi = key >> 5, bi = key & 31u;
    r = wpref[wi] + __popc(bitmap[wi] & ((1u << bi) - 1u));
  }
  unsigned long long m = __ballot(val);
  while(m){
    int b = __ffsll(m) - 1;
    m &= m - 1;
    uint32_t ee = (uint32_t)(base + b);
    uint32_t rr = (uint32_t)__shfl((int)r, b);
    float2 v = ((const float2*)(dx + (size_t)ee*FDIM))[lane];
    atomicAdd(&dsum[(size_t)rr*FDIM + 2*lane], v.x);
    atomicAdd(&dsum[(size_t)rr*FDIM + 2*lane + 1], v.y);
    if(lane == 0) atomicAdd(&dcnt[rr], 1u);
  }
}
// ---- stream the full output region: shadow-summed means for live rows, zeros elsewhere ----
__global__ __launch_bounds__(256) void k_finalize(const float4* psumS, const uint32_t* counts,
        const float4* dsum, const uint32_t* dcnt, const uint32_t* sc, float4* out4){
  uint32_t C = sc[SC_C], U = sc[SC_U];
  size_t cs = (size_t)C * (FDIM/4);          // shadow stride in float4
  size_t gid = (size_t)blockIdx.x*256 + threadIdx.x;
  size_t gs = (size_t)gridDim.x*256;
  const size_t NP4 = (size_t)N_NODES*(FDIM/4);
  const size_t TOT4 = (size_t)(N_NODES + N_EDGES)*(FDIM/4);
  for(size_t j = gid; j < TOT4; j += gs){
    float4 v = make_float4(0.f,0.f,0.f,0.f);
    if(j < NP4){
      uint32_t r = (uint32_t)(j >> 5);
      if(r < C){
        v = psumS[j];
        #pragma unroll
        for(int s = 1; s < NSHAD; s++){
          float4 t = psumS[(size_t)s*cs + j];
          v.x += t.x; v.y += t.y; v.z += t.z; v.w += t.w;
        }
        float fc = (float)counts[r];
        v.x /= fc; v.y /= fc; v.z /= fc; v.w /= fc;
      }
    } else {
      size_t dj = j - NP4;
      uint32_t r = (uint32_t)(dj >> 5);
      if(r < U){
        v = dsum[dj];
        float fc = (float)dcnt[r];
        v.x /= fc; v.y /= fc; v.z /= fc; v.w /= fc;
      }
    }
    out4[j] = v;
  }
}

extern "C" void kernel_launch(void* const* d_in, const int* in_sizes, int n_in,
                              void* d_out, int out_size, void* d_ws, size_t ws_size,
                              hipStream_t stream){
  (void)in_sizes; (void)n_in; (void)out_size;
  const float* primal_x = (const float*)d_in[0];
  const float* dual_x   = (const float*)d_in[1];
  const float* att      = (const float*)d_in[2];
  const int*   pei      = (const int*)d_in[3];
  const int* src = pei;
  const int* dst = pei + N_EDGES;

  float* out  = (float*)d_out;
  float* outE = out + (size_t)(N_NODES + N_EDGES)*FDIM;   // (2, E)
  float* outC = outE + (size_t)2*N_EDGES;                 // (N,)

  uint32_t* w = (uint32_t*)d_ws;
  size_t words_avail = ws_size / 4;
  const size_t PSUMW = (size_t)NSHAD*CMAX*FDIM;            // 16.8M words
  const size_t CNT2W = (size_t)CMAX*NSHAD2;                // 262144 words
  const size_t FIXED = 64 + 1024 + (size_t)N_NODES + CNT2W
                     + TIECAP + 4*(size_t)N_NODES + CNT2W + 4*(size_t)WLCAP
                     + (size_t)N_EDGES + (size_t)N_EDGES   // kc + dcnt
                     + 4096
                     + PSUMW + (size_t)N_EDGES*FDIM;       // psumS + dsum
  size_t wcap = (words_avail > FIXED) ? (words_avail - FIXED)/2 : 4;
  if(wcap > 8388608) wcap = 8388608;   // supports C up to 16384
  wcap &= ~(size_t)3;

  size_t o = 0;
  uint32_t* sc      = w;               o += 64;
  uint32_t* hists   = w + o;           o += 1024;          // 4 x 256
  uint32_t* counts  = w + o;           o += N_NODES;
  uint32_t* counts2 = w + o;           o += CNT2W;
  size_t zero_words = o;                                    // zeroed per call
  uint32_t* tieIdx  = w + o;           o += TIECAP;
  int* labels       = (int*)(w + o);   o += N_NODES;
  uint32_t* rank_   = w + o;           o += N_NODES;
  int* cluster_i    = (int*)(w + o);   o += N_NODES;
  uint32_t* order   = w + o;           o += N_NODES;
  uint32_t* cursor2 = w + o;           o += CNT2W;
  uint2* wl0        = (uint2*)(w + o); o += 2*(size_t)WLCAP;
  uint2* wl1        = (uint2*)(w + o); o += 2*(size_t)WLCAP;
  uint32_t* kc      = w + o;           o += N_EDGES;
  uint32_t* dcnt    = w + o;           o += N_EDGES;
  uint32_t* bsums   = w + o;           o += 4096;
  float* psumS      = (float*)(w + o); o += PSUMW;
  float* dsum       = (float*)(w + o); o += (size_t)N_EDGES*FDIM;
  uint32_t* bitmap  = w + o;           o += wcap;
  uint32_t* wpref   = w + o;           o += wcap;

  const int EB  = (N_EDGES + 255)/256;
  const int NB  = (N_NODES + 255)/256;
  const int WSB = (int)((wcap + 2047)/2048);           // <= 4096

  k_zero<<<128,256,0,stream>>>(w, (uint32_t)zero_words);
  // selection: 4 hist levels (prior digits recomputed in-block; L init fused in L1)
  k_hist8<1><<<HB,256,0,stream>>>(att, hists, labels);
  k_hist8<2><<<HB,256,0,stream>>>(att, hists, labels);
  k_hist8<3><<<HB,256,0,stream>>>(att, hists, labels);
  k_hist8<4><<<HB,256,0,stream>>>(att, hists, labels);
  // CC: seed + tie handling + relax/jump ladder (per-round counter slots, never reset)
  k_seed<<<EB,256,0,stream>>>(att, src, dst, hists, sc, tieIdx, labels, wl0);
  k_tiesel<<<1,1024,0,stream>>>(sc, tieIdx, src, dst, labels, wl0);
  for(int r = 1; r <= 8; ++r){
    uint2* win  = (r & 1) ? wl0 : wl1;
    uint2* wout = (r & 1) ? wl1 : wl0;
    k_relax<<<1024,256,0,stream>>>(win, wout, labels, sc, SC_WL0 + r - 1, SC_WL0 + r);
    if(r <= 3) k_jump<<<NB,256,0,stream>>>(labels, sc, SC_WL0 + r);
  }
  k_flatten_reduce<<<NSB,256,0,stream>>>(labels, bsums);
  k_scan_apply<2><<<NSB,256,0,stream>>>(counts, labels, bsums, NSB, rank_, sc);   // -> rank_, SC_C, SC_W
  k_cluster_counts<<<NB,256,0,stream>>>(labels, rank_, cluster_i, outC, counts, counts2,
                                        psumS, bitmap, sc);
  k_scan_reduce<3><<<CS2B,256,0,stream>>>(counts2, bsums, sc, dsum, dcnt);
  k_scan_apply<3><<<CS2B,256,0,stream>>>(counts2, labels, bsums, CS2B, cursor2, sc); // -> cursor2
  k_scatter<<<NB,256,0,stream>>>(cluster_i, cursor2, order);
  k_seg_edges<<<SGB + EB,256,0,stream>>>(primal_x, order, cluster_i, psumS,
                                         src, dst, sc, outE, kc, bitmap);
  k_scan_reduce<1><<<WSB,256,0,stream>>>(bitmap, bsums, sc, dsum, dcnt);          // + lazy zero dsum/dcnt
  k_scan_apply<1><<<WSB,256,0,stream>>>(bitmap, labels, bsums, WSB, wpref, sc);   // -> wpref, SC_U
  k_dualacc<<<EB,256,0,stream>>>(dual_x, kc, bitmap, wpref, dsum, dcnt);
  k_finalize<<<2048,256,0,stream>>>((const float4*)psumS, counts, (const float4*)dsum,
                                    dcnt, sc, (float4*)out);
}

// Round 13
// 626.576 us; speedup vs baseline: 1.4936x; 1.1251x over previous
//
#include <hip/hip_runtime.h>
#include <stdint.h>

// DualPrimalEdgePooling on MI355X — 26 dispatches.
// radix-select -> worklist min-label CC (jump fused into relax VIA ATOMICMIN,
// block-agg appends) -> fused flatten/scan/cluster -> 16-shadow counting-sort
// scatter -> 128-rows/wave shfl-broadcast segmented mean into 8 shadow
// accumulators (fused with edges+bitmap) -> popcount-prefix dual ranking ->
// finalize streams the full output.

#define N_NODES 200000
#define N_EDGES 600000
#define FDIM 128
#define NUM_POOL 300000u  // = E - NUM_KEEP

#define SC_NEEDEQ 3
#define SC_TIECNT 4
#define SC_C 5
#define SC_W 6
#define SC_U 7
#define SC_VCNT 8
#define SC_WL0 16        // per-round worklist counters: slots 16..24 (never reset)
#define TIECAP 4096
#define WLCAP 300800
#define HB 256           // hist grid blocks
#define NSB 98           // ceil(N/2048)
#define NSHAD 8          // psum shadow copies (atomic-depth divider)
#define NSHAD2 16        // scatter cursor shadows
#define CMAX 16384       // max clusters supported (bitmap/pair-key bound)
#define SROWS 128        // rows per wave in segsum
#define SGB 391          // ceil(N/(SROWS*4)) segsum blocks
#define CS2B 128         // scan blocks for counts2 (CMAX*16/2048)

__device__ __forceinline__ uint32_t f2ou(float f){
  uint32_t b = __float_as_uint(f);
  return (b & 0x80000000u) ? ~b : (b | 0x80000000u);
}

// block-wide digit selection from a completed 256-bin histogram (blockDim=256)
static __device__ __forceinline__ void sel_level(const uint32_t* hist, uint32_t& target,
                                                 uint32_t& pfx, uint32_t* sm, uint32_t* res){
  int t = threadIdx.x;
  uint32_t cnt = hist[t];
  sm[t] = cnt; __syncthreads();
  for(int off = 1; off < 256; off <<= 1){
    uint32_t y = (t + off < 256) ? sm[t + off] : 0u;
    __syncthreads(); sm[t] += y; __syncthreads();
  }
  uint32_t suffix = sm[t];            // candidates with digit >= t
  uint32_t above  = suffix - cnt;
  if(above < target && target <= suffix){ res[0] = (uint32_t)t; res[1] = target - above; }
  __syncthreads();
  pfx = (pfx << 8) | res[0];
  target = res[1];
  __syncthreads();
}

// block-wide exclusive scan of one value per thread (blockDim=256)
static __device__ __forceinline__ uint32_t blk_excl(uint32_t v, uint32_t* sm, uint32_t& total){
  int t = threadIdx.x;
  sm[t] = v; __syncthreads();
  for(int off = 1; off < 256; off <<= 1){
    uint32_t y = (t >= off) ? sm[t - off] : 0u;
    __syncthreads(); sm[t] += y; __syncthreads();
  }
  total = sm[255];
  uint32_t incl = sm[t];
  __syncthreads();
  return incl - v;
}

// ---- tiny ws zero (sc + hists + counts + counts2), vectorized ----
__global__ __launch_bounds__(256) void k_zero(uint4* w4, uint32_t n4){
  uint32_t gid = blockIdx.x*256 + threadIdx.x;
  uint4 z = make_uint4(0u,0u,0u,0u);
  for(uint32_t j = gid; j < n4; j += gridDim.x*256) w4[j] = z;
}

// ---- selection: 4-level 8-bit radix histograms; prior-level digits recomputed in-block ----
template<int LEVEL>
__global__ __launch_bounds__(256) void k_hist8(const float* att, uint32_t* hists, int* L){
  __shared__ uint32_t h[256];
  __shared__ uint32_t sm[256];
  __shared__ uint32_t res[2];
  h[threadIdx.x] = 0;
  if(LEVEL == 1){
    for(int i = blockIdx.x*256 + threadIdx.x; i < N_NODES; i += HB*256) L[i] = i;  // fused CC init
  }
  __syncthreads();
  uint32_t pfx = 0, target = NUM_POOL;
  #pragma unroll
  for(int l = 0; l < LEVEL-1; ++l) sel_level(hists + 256*l, target, pfx, sm, res);
  constexpr int SH1 = (LEVEL > 1) ? 8*(5-LEVEL) : 0;
  constexpr int SH2 = 8*(4-LEVEL);
  for(int e = blockIdx.x*256 + threadIdx.x; e < N_EDGES; e += HB*256){
    uint32_t u = f2ou(att[e]);
    bool ok = (LEVEL == 1) || ((u >> SH1) == pfx);
    if(ok) atomicAdd(&h[(u >> SH2) & 0xFFu], 1u);
  }
  __syncthreads();
  uint32_t c = h[threadIdx.x];
  if(c) atomicAdd(&hists[256*(LEVEL-1) + threadIdx.x], c);
}

// ---- seed: recompute threshold in-block; pooled edges hook + block-agg worklist append ----
__global__ __launch_bounds__(256) void k_seed(const float* att, const int* src, const int* dst,
                       const uint32_t* hists, uint32_t* sc, uint32_t* tieIdx, int* L, uint2* wl){
  __shared__ uint32_t sm[256];
  __shared__ uint32_t res[2];
  __shared__ uint32_t basesh;
  uint32_t pfx = 0, target = NUM_POOL;
  #pragma unroll
  for(int l = 0; l < 4; ++l) sel_level(hists + 256*l, target, pfx, sm, res);
  if(blockIdx.x == 0 && threadIdx.x == 0) sc[SC_NEEDEQ] = target;
  uint32_t T = pfx;
  int e = blockIdx.x*256 + threadIdx.x;
  bool app = false; int u = 0, v = 0;
  if(e < N_EDGES){
    uint32_t ub = f2ou(att[e]);
    if(ub > T){
      u = src[e]; v = dst[e];
      if(u != v){
        int m = u < v ? u : v, hi = u ^ v ^ m;
        atomicMin(&L[hi], m);
        app = true;
      }
    } else if(ub == T){
      uint32_t p = atomicAdd(&sc[SC_TIECNT], 1u);
      if(p < TIECAP) tieIdx[p] = (uint32_t)e;
    }
  }
  uint32_t tot;
  uint32_t off = blk_excl(app ? 1u : 0u, sm, tot);
  if(threadIdx.x == 0 && tot) basesh = atomicAdd(&sc[SC_WL0], tot);
  __syncthreads();
  if(app) wl[basesh + off] = make_uint2((uint32_t)(u < v ? u : v), (uint32_t)(u > v ? u : v));
}
__global__ __launch_bounds__(1024) void k_tiesel(uint32_t* sc, const uint32_t* tieIdx,
                        const int* src, const int* dst, int* L, uint2* wl){
  uint32_t m = sc[SC_TIECNT]; if(m > TIECAP) m = TIECAP;
  uint32_t need = sc[SC_NEEDEQ];
  int lane = threadIdx.x & 63;
  for(uint32_t i0 = 0; i0 < m; i0 += 1024){
    uint32_t i = i0 + threadIdx.x;
    bool app = false; int u = 0, v = 0;
    if(i < m){
      uint32_t mine = tieIdx[i];
      uint32_t r = 0;
      for(uint32_t j = 0; j < m; j++) r += (tieIdx[j] < mine) ? 1u : 0u;
      if(r < need){   // stable argsort: smallest indices pooled
        u = src[mine]; v = dst[mine];
        if(u != v){ int mm = u < v ? u : v, hi = u ^ v ^ mm; atomicMin(&L[hi], mm); app = true; }
      }
    }
    unsigned long long grp = __ballot(app);
    if(grp){
      int leader = __ffsll(grp) - 1;
      uint32_t base = 0;
      if(lane == leader) base = atomicAdd(&sc[SC_WL0], (uint32_t)__popcll(grp));
      base = (uint32_t)__shfl((int)base, leader);
      if(app){
        uint32_t off = (uint32_t)__popcll(grp & ((1ull << lane) - 1ull));
        wl[base + off] = make_uint2((uint32_t)(u < v ? u : v), (uint32_t)(u > v ? u : v));
      }
    }
  }
}
// relax + fused pointer jump: 4-level chase (plain loads), one-shot hooking atomicMin,
// survivors re-appended via block-agg. Jump slice uses ATOMICMIN (not plain store):
// concurrent hooks from other blocks can never be lost (monotone decrease only).
__global__ __launch_bounds__(256) void k_relax(const uint2* wl_in, uint2* wl_out, int* L,
                       uint32_t* sc, int inSlot, int outSlot){
  __shared__ uint32_t sm[256];
  __shared__ uint32_t basesh;
  uint32_t n = sc[inSlot];
  for(uint32_t base = blockIdx.x*256u; base < n; base += gridDim.x*256u){
    uint32_t idx = base + threadIdx.x;
    bool active = idx < n;
    int lu = 0, lv = 0;
    if(active){
      uint2 ed = wl_in[idx];
      lu = L[ed.x]; lu = L[lu]; lu = L[lu]; lu = L[lu];
      lv = L[ed.y]; lv = L[lv]; lv = L[lv]; lv = L[lv];
      active = (lu != lv);
      if(active){
        int m = lu < lv ? lu : lv, hi = lu ^ lv ^ m;
        atomicMin(&L[hi], m);
      }
    }
    uint32_t tot;
    uint32_t off = blk_excl(active ? 1u : 0u, sm, tot);
    if(threadIdx.x == 0 && tot) basesh = atomicAdd(&sc[outSlot], tot);
    __syncthreads();
    if(active) wl_out[basesh + off] = make_uint2((uint32_t)(lu < lv ? lu : lv),
                                                 (uint32_t)(lu > lv ? lu : lv));
  }
  if(n != 0){   // fused jump slice: monotone atomicMin => race-free vs concurrent hooks
    int i = blockIdx.x*256 + threadIdx.x;
    if(i < N_NODES){
      int v = L[i]; v = L[v]; v = L[v]; v = L[v];
      if(v < i) atomicMin(&L[i], v);
    }
  }
}
// flatten to roots + per-block root-count reduction (2048 nodes/block)
__global__ __launch_bounds__(256) void k_flatten_reduce(int* L, uint32_t* bsums){
  uint32_t base = blockIdx.x*2048u + threadIdx.x*8u;
  uint32_t s = 0;
  #pragma unroll
  for(int k = 0; k < 8; k++){
    uint32_t i = base + k;
    if(i < N_NODES){
      int p = L[i]; int q = L[p];
      while(q != p){ p = q; q = L[p]; }
      L[i] = p;
      s += (p == (int)i) ? 1u : 0u;
    }
  }
  __shared__ uint32_t sm[256];
  sm[threadIdx.x] = s; __syncthreads();
  for(int off = 128; off > 0; off >>= 1){
    if((int)threadIdx.x < off) sm[threadIdx.x] += sm[threadIdx.x + off];
    __syncthreads();
  }
  if(threadIdx.x == 0) bsums[blockIdx.x] = sm[0];
}

// ---- 2-kernel scans. MODE 1: popc(bitmap)->wpref (+SC_U). MODE 2: rootflag(L)->rank_
//      (+SC_C,SC_W). MODE 3: counts2->cursor2 (n = C*NSHAD2). apply scans bsums in-LDS. ----
template<int MODE>
__device__ __forceinline__ uint32_t scan_n(const uint32_t* sc){
  if(MODE == 1) return sc[SC_W];
  if(MODE == 3) return sc[SC_C]*NSHAD2;
  return N_NODES;
}
template<int MODE>
__global__ __launch_bounds__(256) void k_scan_reduce(const uint32_t* in, uint32_t* bsums,
                       const uint32_t* sc, float* dsum, uint32_t* dcnt){
  uint32_t n = scan_n<MODE>(sc);
  if(MODE == 1){  // lazy-zero compact dual accumulators (VCNT rows >= U), vectorized
    uint32_t vc = sc[SC_VCNT];
    size_t gid = (size_t)blockIdx.x*256 + threadIdx.x, gs = (size_t)gridDim.x*256;
    float4* d4 = (float4*)dsum;
    float4 z = make_float4(0.f,0.f,0.f,0.f);
    for(size_t j = gid; j < (size_t)vc*(FDIM/4); j += gs) d4[j] = z;
    for(size_t j = gid; j < vc; j += gs) dcnt[j] = 0u;
  }
  uint32_t base = blockIdx.x*2048u + threadIdx.x*8u;
  uint32_t s = 0;
  #pragma unroll
  for(int k = 0; k < 8; k++){
    uint32_t idx = base + k;
    if(idx < n){ uint32_t v = in[idx]; if(MODE == 1) v = __popc(v); s += v; }
  }
  __shared__ uint32_t sm[256];
  sm[threadIdx.x] = s; __syncthreads();
  for(int off = 128; off > 0; off >>= 1){
    if((int)threadIdx.x < off) sm[threadIdx.x] += sm[threadIdx.x + off];
    __syncthreads();
  }
  if(threadIdx.x == 0) bsums[blockIdx.x] = sm[0];
}
template<int MODE>
__global__ __launch_bounds__(256) void k_scan_apply(const uint32_t* in, const int* L,
                       const uint32_t* bsums, int nb, uint32_t* out, uint32_t* sc){
  __shared__ uint32_t bs[4096];
  __shared__ uint32_t sm[256];
  int t = threadIdx.x;
  uint32_t n = scan_n<MODE>(sc);
  uint32_t loc[16]; uint32_t ls = 0;
  #pragma unroll
  for(int k = 0; k < 16; k++){ int idx = t*16 + k; uint32_t v = (idx < nb) ? bsums[idx] : 0u; loc[k] = v; ls += v; }
  sm[t] = ls; __syncthreads();
  for(int off = 1; off < 256; off <<= 1){
    uint32_t y = (t >= off) ? sm[t - off] : 0u;
    __syncthreads(); sm[t] += y; __syncthreads();
  }
  uint32_t total = sm[255];
  uint32_t run = sm[t] - ls;
  #pragma unroll
  for(int k = 0; k < 16; k++){ bs[t*16 + k] = run; run += loc[k]; }
  __syncthreads();
  uint32_t blockbase = bs[blockIdx.x];
  __syncthreads();
  uint32_t base = blockIdx.x*2048u + t*8u;
  uint32_t xs[8]; uint32_t ts2 = 0;
  #pragma unroll
  for(int k = 0; k < 8; k++){
    uint32_t idx = base + k; uint32_t v = 0;
    if(idx < n){
      if(MODE == 2) v = (L[idx] == (int)idx) ? 1u : 0u;
      else { v = in[idx]; if(MODE == 1) v = __popc(v); }
    }
    xs[k] = v; ts2 += v;
  }
  sm[t] = ts2; __syncthreads();
  for(int off = 1; off < 256; off <<= 1){
    uint32_t y = (t >= off) ? sm[t - off] : 0u;
    __syncthreads(); sm[t] += y; __syncthreads();
  }
  uint32_t run2 = blockbase + sm[t] - ts2;
  #pragma unroll
  for(int k = 0; k < 8; k++){ uint32_t idx = base + k; if(idx < n) out[idx] = run2; run2 += xs[k]; }
  if(blockIdx.x == 0 && t == 0){
    if(MODE == 2){ sc[SC_C] = total; uint64_t cc = (uint64_t)total*(uint64_t)total; sc[SC_W] = (uint32_t)((cc + 31ull) >> 5); }
    if(MODE == 1){ sc[SC_U] = total; }
  }
}

// ---- cluster ids + wave-agg counts (total + per-shadow) + lazy zero psumS/bitmap ----
__global__ __launch_bounds__(256) void k_cluster_counts(const int* L, const uint32_t* rank_,
                       int* cluster_i, float* outC, uint32_t* counts, uint32_t* counts2,
                       float* psumS, uint32_t* bitmap, const uint32_t* sc){
  uint32_t C = sc[SC_C], W = sc[SC_W];
  uint32_t gid = blockIdx.x*256 + threadIdx.x, gs = gridDim.x*256;
  float4* p4 = (float4*)psumS;
  float4 z = make_float4(0.f,0.f,0.f,0.f);
  for(size_t j = gid; j < (size_t)NSHAD*C*(FDIM/4); j += gs) p4[j] = z;
  for(uint32_t j = gid; j < W; j += gs) bitmap[j] = 0u;
  int i = (int)gid;
  int lane = threadIdx.x & 63;
  int sh = (int)((gid >> 6) & (NSHAD2-1));
  int c = -1;
  if(i < N_NODES){
    c = (int)rank_[L[i]];
    cluster_i[i] = c;
    outC[i] = (float)c;
  }
  unsigned long long remaining = __ballot(i < N_NODES);
  while(remaining){
    int leader = __ffsll(remaining) - 1;
    int lc = __shfl(c, leader);
    unsigned long long grp = __ballot(c == lc) & remaining;
    if(lane == leader){
      uint32_t cnt = (uint32_t)__popcll(grp);
      atomicAdd(&counts[lc], cnt);                       // fire-and-forget (means)
      atomicAdd(&counts2[lc*NSHAD2 + sh], cnt);          // per-shadow capacity
    }
    remaining &= ~grp;
  }
}
// scatter via 16-shadow cursors: same grid geometry as k_cluster_counts => exact capacities
__global__ void k_scatter(const int* cluster_i, uint32_t* cursor2, uint32_t* order){
  uint32_t gid = blockIdx.x*256 + threadIdx.x;
  int i = (int)gid;
  int lane = threadIdx.x & 63;
  int sh = (int)((gid >> 6) & (NSHAD2-1));
  int c = (i < N_NODES) ? cluster_i[i] : -1;
  unsigned long long remaining = __ballot(i < N_NODES);
  while(remaining){
    int leader = __ffsll(remaining) - 1;
    int lc = __shfl(c, leader);
    unsigned long long grp = __ballot(c == lc) & remaining;
    int b = 0;
    if(lane == leader) b = (int)atomicAdd(&cursor2[lc*NSHAD2 + sh], (uint32_t)__popcll(grp));
    b = __shfl(b, leader);
    if((grp >> lane) & 1ull){
      uint32_t sub = (uint32_t)__popcll(grp & ((1ull << lane) - 1ull));
      order[(uint32_t)b + sub] = (uint32_t)i;
    }
    remaining &= ~grp;
  }
}

// ---- fused: segmented mean into 8-shadow psum (blocks < SGB) | edges+bitmap (rest) ----
__global__ __launch_bounds__(256) void k_seg_edges(const float* px, const uint32_t* order,
        const int* cluster_i, float* psumS, const int* src, const int* dst, uint32_t* sc,
        float* outE, uint32_t* kc, uint32_t* bitmap){
  if(blockIdx.x < SGB){
    int wave = (int)((blockIdx.x*256u + threadIdx.x) >> 6);
    int lane = threadIdx.x & 63;
    int start = wave * SROWS;
    if(start >= N_NODES) return;
    int cnt = N_NODES - start; if(cnt > SROWS) cnt = SROWS;
    size_t shadBase = (size_t)(wave & (NSHAD-1)) * (size_t)sc[SC_C] * FDIM;
    uint32_t ord0 = 0, ord1 = 0; int c0 = -1, c1 = -1;
    if(lane < cnt){ ord0 = order[start + lane]; c0 = cluster_i[ord0]; }
    if(64 + lane < cnt){ ord1 = order[start + 64 + lane]; c1 = cluster_i[ord1]; }
    float ax = 0.f, ay = 0.f; int cur = -1;
    for(int r = 0; r < cnt; r++){
      uint32_t i; int c;
      if(r < 64){ i = (uint32_t)__shfl((int)ord0, r); c = __shfl(c0, r); }
      else      { i = (uint32_t)__shfl((int)ord1, r - 64); c = __shfl(c1, r - 64); }
      if(c != cur){
        if(cur >= 0){
          atomicAdd(&psumS[shadBase + (size_t)cur*FDIM + 2*lane], ax);
          atomicAdd(&psumS[shadBase + (size_t)cur*FDIM + 2*lane + 1], ay);
        }
        cur = c; ax = 0.f; ay = 0.f;
      }
      float2 v = ((const float2*)(px + (size_t)i*FDIM))[lane];
      ax += v.x; ay += v.y;
    }
    if(cur >= 0){
      atomicAdd(&psumS[shadBase + (size_t)cur*FDIM + 2*lane], ax);
      atomicAdd(&psumS[shadBase + (size_t)cur*FDIM + 2*lane + 1], ay);
    }
  } else {
    __shared__ uint32_t wsum[4];
    int e = (blockIdx.x - SGB)*256 + threadIdx.x;
    int lane = threadIdx.x & 63;
    int wv = threadIdx.x >> 6;
    bool val = false;
    if(e < N_EDGES){
      int cu = cluster_i[src[e]];
      int cv = cluster_i[dst[e]];
      val = (cu != cv);
      outE[e] = val ? (float)cu : -1.0f;
      outE[N_EDGES + e] = val ? (float)cv : -1.0f;
      if(val){
        int a = cu < cv ? cu : cv, b = cu < cv ? cv : cu;
        uint32_t C = sc[SC_C];
        uint32_t key = (uint32_t)a * C + (uint32_t)b;
        kc[e] = key;
        atomicOr(&bitmap[key >> 5], 1u << (key & 31u));
      } else {
        kc[e] = 0xFFFFFFFFu;
      }
    }
    unsigned long long grp = __ballot(val);
    if(lane == 0) wsum[wv] = (uint32_t)__popcll(grp);
    __syncthreads();
    if(threadIdx.x == 0){
      uint32_t s = wsum[0] + wsum[1] + wsum[2] + wsum[3];
      if(s) atomicAdd(&sc[SC_VCNT], s);   // fire-and-forget (upper bound for dsum zeroing)
    }
  }
}

// ---- dual accumulate: 64 edges/wave, ballot + shfl-broadcast rank ----
__global__ __launch_bounds__(256) void k_dualacc(const float* dx, const uint32_t* kc,
                          const uint32_t* bitmap, const uint32_t* wpref,
                          float* dsum, uint32_t* dcnt){
  int wave = (int)((blockIdx.x*256u + threadIdx.x) >> 6);
  int lane = threadIdx.x & 63;
  int base = wave * 64;
  if(base >= N_EDGES) return;
  int e = base + lane;
  uint32_t key = (e < N_EDGES) ? kc[e] : 0xFFFFFFFFu;
  bool val = (key != 0xFFFFFFFFu);
  uint32_t r = 0;
  if(val){
    uint32_t wi = key >> 5, bi = key & 31u;
    r = wpref[wi] + __popc(bitmap[wi] & ((1u << bi) - 1u));
  }
  unsigned long long m = __ballot(val);
  while(m){
    int b = __ffsll(m) - 1;
    m &= m - 1;
    uint32_t ee = (uint32_t)(base + b);
    uint32_t rr = (uint32_t)__shfl((int)r, b);
    float2 v = ((const float2*)(dx + (size_t)ee*FDIM))[lane];
    atomicAdd(&dsum[(size_t)rr*FDIM + 2*lane], v.x);
    atomicAdd(&dsum[(size_t)rr*FDIM + 2*lane + 1], v.y);
    if(lane == 0) atomicAdd(&dcnt[rr], 1u);
  }
}
// ---- stream the full output region: shadow-summed means for live rows, zeros elsewhere ----
__global__ __launch_bounds__(256) void k_finalize(const float4* psumS, const uint32_t* counts,
        const float4* dsum, const uint32_t* dcnt, const uint32_t* sc, float4* out4){
  uint32_t C = sc[SC_C], U = sc[SC_U];
  size_t cs = (size_t)C * (FDIM/4);          // shadow stride in float4
  size_t gid = (size_t)blockIdx.x*256 + threadIdx.x;
  size_t gs = (size_t)gridDim.x*256;
  const size_t NP4 = (size_t)N_NODES*(FDIM/4);
  const size_t TOT4 = (size_t)(N_NODES + N_EDGES)*(FDIM/4);
  for(size_t j = gid; j < TOT4; j += gs){
    float4 v = make_float4(0.f,0.f,0.f,0.f);
    if(j < NP4){
      uint32_t r = (uint32_t)(j >> 5);
      if(r < C){
        v = psumS[j];
        #pragma unroll
        for(int s = 1; s < NSHAD; s++){
          float4 t = psumS[(size_t)s*cs + j];
          v.x += t.x; v.y += t.y; v.z += t.z; v.w += t.w;
        }
        float fc = (float)counts[r];
        v.x /= fc; v.y /= fc; v.z /= fc; v.w /= fc;
      }
    } else {
      size_t dj = j - NP4;
      uint32_t r = (uint32_t)(dj >> 5);
      if(r < U){
        v = dsum[dj];
        float fc = (float)dcnt[r];
        v.x /= fc; v.y /= fc; v.z /= fc; v.w /= fc;
      }
    }
    out4[j] = v;
  }
}

extern "C" void kernel_launch(void* const* d_in, const int* in_sizes, int n_in,
                              void* d_out, int out_size, void* d_ws, size_t ws_size,
                              hipStream_t stream){
  (void)in_sizes; (void)n_in; (void)out_size;
  const float* primal_x = (const float*)d_in[0];
  const float* dual_x   = (const float*)d_in[1];
  const float* att      = (const float*)d_in[2];
  const int*   pei      = (const int*)d_in[3];
  const int* src = pei;
  const int* dst = pei + N_EDGES;

  float* out  = (float*)d_out;
  float* outE = out + (size_t)(N_NODES + N_EDGES)*FDIM;   // (2, E)
  float* outC = outE + (size_t)2*N_EDGES;                 // (N,)

  uint32_t* w = (uint32_t*)d_ws;
  size_t words_avail = ws_size / 4;
  const size_t PSUMW = (size_t)NSHAD*CMAX*FDIM;            // 16.8M words
  const size_t CNT2W = (size_t)CMAX*NSHAD2;                // 262144 words
  const size_t FIXED = 64 + 1024 + (size_t)N_NODES + CNT2W
                     + TIECAP + 4*(size_t)N_NODES + CNT2W + 4*(size_t)WLCAP
                     + (size_t)N_EDGES + (size_t)N_EDGES   // kc + dcnt
                     + 4096
                     + PSUMW + (size_t)N_EDGES*FDIM;       // psumS + dsum
  size_t wcap = (words_avail > FIXED) ? (words_avail - FIXED)/2 : 4;
  if(wcap > 8388608) wcap = 8388608;   // supports C up to 16384
  wcap &= ~(size_t)3;

  size_t o = 0;
  uint32_t* sc      = w;               o += 64;
  uint32_t* hists   = w + o;           o += 1024;          // 4 x 256
  uint32_t* counts  = w + o;           o += N_NODES;
  uint32_t* counts2 = w + o;           o += CNT2W;
  size_t zero_words = o;                                    // zeroed per call (mult of 4)
  uint32_t* tieIdx  = w + o;           o += TIECAP;
  int* labels       = (int*)(w + o);   o += N_NODES;
  uint32_t* rank_   = w + o;           o += N_NODES;
  int* cluster_i    = (int*)(w + o);   o += N_NODES;
  uint32_t* order   = w + o;           o += N_NODES;
  uint32_t* cursor2 = w + o;           o += CNT2W;
  uint2* wl0        = (uint2*)(w + o); o += 2*(size_t)WLCAP;
  uint2* wl1        = (uint2*)(w + o); o += 2*(size_t)WLCAP;
  uint32_t* kc      = w + o;           o += N_EDGES;
  uint32_t* dcnt    = w + o;           o += N_EDGES;
  uint32_t* bsums   = w + o;           o += 4096;
  float* psumS      = (float*)(w + o); o += PSUMW;
  float* dsum       = (float*)(w + o); o += (size_t)N_EDGES*FDIM;
  uint32_t* bitmap  = w + o;           o += wcap;
  uint32_t* wpref   = w + o;           o += wcap;

  const int EB  = (N_EDGES + 255)/256;
  const int NB  = (N_NODES + 255)/256;
  const int WSB = (int)((wcap + 2047)/2048);           // <= 4096

  k_zero<<<128,256,0,stream>>>((uint4*)w, (uint32_t)(zero_words/4));
  // selection: 4 hist levels (prior digits recomputed in-block; L init fused in L1)
  k_hist8<1><<<HB,256,0,stream>>>(att, hists, labels);
  k_hist8<2><<<HB,256,0,stream>>>(att, hists, labels);
  k_hist8<3><<<HB,256,0,stream>>>(att, hists, labels);
  k_hist8<4><<<HB,256,0,stream>>>(att, hists, labels);
  // CC: seed + tie handling + relax ladder (jump fused via atomicMin)
  k_seed<<<EB,256,0,stream>>>(att, src, dst, hists, sc, tieIdx, labels, wl0);
  k_tiesel<<<1,1024,0,stream>>>(sc, tieIdx, src, dst, labels, wl0);
  for(int r = 1; r <= 8; ++r){
    uint2* win  = (r & 1) ? wl0 : wl1;
    uint2* wout = (r & 1) ? wl1 : wl0;
    k_relax<<<1024,256,0,stream>>>(win, wout, labels, sc, SC_WL0 + r - 1, SC_WL0 + r);
  }
  k_flatten_reduce<<<NSB,256,0,stream>>>(labels, bsums);
  k_scan_apply<2><<<NSB,256,0,stream>>>(counts, labels, bsums, NSB, rank_, sc);   // -> rank_, SC_C, SC_W
  k_cluster_counts<<<NB,256,0,stream>>>(labels, rank_, cluster_i, outC, counts, counts2,
                                        psumS, bitmap, sc);
  k_scan_reduce<3><<<CS2B,256,0,stream>>>(counts2, bsums, sc, dsum, dcnt);
  k_scan_apply<3><<<CS2B,256,0,stream>>>(counts2, labels, bsums, CS2B, cursor2, sc); // -> cursor2
  k_scatter<<<NB,256,0,stream>>>(cluster_i, cursor2, order);
  k_seg_edges<<<SGB + EB,256,0,stream>>>(primal_x, order, cluster_i, psumS,
                                         src, dst, sc, outE, kc, bitmap);
  k_scan_reduce<1><<<WSB,256,0,stream>>>(bitmap, bsums, sc, dsum, dcnt);          // + lazy zero dsum/dcnt
  k_scan_apply<1><<<WSB,256,0,stream>>>(bitmap, labels, bsums, WSB, wpref, sc);   // -> wpref, SC_U
  k_dualacc<<<EB,256,0,stream>>>(dual_x, kc, bitmap, wpref, dsum, dcnt);
  k_finalize<<<2048,256,0,stream>>>((const float4*)psumS, counts, (const float4*)dsum,
                                    dcnt, sc, (float4*)out);
}